// Round 1
// baseline (3943.897 us; speedup 1.0000x reference)
//
#include <hip/hip_runtime.h>

#define EPSF 1e-7f

__device__ __forceinline__ float lrelu02(float x){ return x > 0.f ? x : 0.2f*x; }

// float atomic max via int max (>=0) / uint min (<0). Works with -inf init.
__device__ __forceinline__ void atomicMaxF(float* addr, float val) {
  if (val >= 0.f) atomicMax((int*)addr, __float_as_int(val));
  else            atomicMin((unsigned int*)addr, __float_as_uint(val));
}

// ---------------- init: zeros + (-inf) for segment-max ----------------
__global__ void k_init(float* __restrict__ agg1, float* __restrict__ agg2,
                       float* __restrict__ denom1, float* __restrict__ denom2,
                       float* __restrict__ emax1, float* __restrict__ emax2, int N) {
  int stride = gridDim.x * blockDim.x;
  int total = N * 256;
  float ninf = -__builtin_inff();
  for (int i = blockIdx.x*blockDim.x + threadIdx.x; i < total; i += stride) {
    agg1[i] = 0.f;
    if (i < N*64) agg2[i] = 0.f;
    if (i < N*4) { denom1[i] = 0.f; emax1[i] = ninf; }
    if (i < N)   { denom2[i] = 0.f; emax2[i] = ninf; }
  }
}

// ------------- layer1: logmap0(x) @ W1 -> h1 [N,256]; es1/ed1 [N,4] -------------
__global__ __launch_bounds__(256) void k_gemm1(
    const float* __restrict__ x, const float* __restrict__ W1,
    const float* __restrict__ a_src, const float* __restrict__ a_dst,
    float* __restrict__ h1, float* __restrict__ es, float* __restrict__ ed, int N) {
  __shared__ float t[8][128];
  const int tid = threadIdx.x;
  const int block0 = blockIdx.x * 8;
  // load 8 rows x 128, 32 threads/row, float4 each; per-row norm via 32-lane shfl
  {
    const int r = tid >> 5, c = (tid & 31) * 4;
    const int row = block0 + r;
    float4 v = make_float4(0.f,0.f,0.f,0.f);
    if (row < N) v = *(const float4*)(x + (size_t)row*128 + c);
    float ss = v.x*v.x + v.y*v.y + v.z*v.z + v.w*v.w;
    #pragma unroll
    for (int o = 16; o; o >>= 1) ss += __shfl_xor(ss, o);
    float n  = fmaxf(sqrtf(ss), EPSF);
    float nc = fminf(n, 1.f - 1e-5f);
    float sc = atanhf(nc) / n;                 // logmap0 scale
    *(float4*)&t[r][c] = make_float4(v.x*sc, v.y*sc, v.z*sc, v.w*sc);
  }
  __syncthreads();

  const int j = tid;                            // output column 0..255
  float acc[8] = {0,0,0,0,0,0,0,0};
  for (int k = 0; k < 128; k += 4) {
    float w0 = W1[(size_t)(k+0)*256 + j];
    float w1 = W1[(size_t)(k+1)*256 + j];
    float w2 = W1[(size_t)(k+2)*256 + j];
    float w3 = W1[(size_t)(k+3)*256 + j];
    #pragma unroll
    for (int rr = 0; rr < 8; ++rr) {
      float4 tv = *(const float4*)&t[rr][k];   // broadcast, conflict-free
      acc[rr] += w0*tv.x + w1*tv.y + w2*tv.z + w3*tv.w;
    }
  }
  const int head = tid >> 6, lane = tid & 63;   // wave == head
  const float as = a_src[head*64 + lane];
  const float ad = a_dst[head*64 + lane];
  #pragma unroll
  for (int rr = 0; rr < 8; ++rr) {
    int rown = block0 + rr;
    if (rown >= N) break;                       // uniform per block
    float hv = acc[rr];
    h1[(size_t)rown*256 + j] = hv;
    float ps = hv * as, pd = hv * ad;
    #pragma unroll
    for (int o = 32; o; o >>= 1) { ps += __shfl_xor(ps, o); pd += __shfl_xor(pd, o); }
    if (lane == 0) { es[rown*4 + head] = ps; ed[rown*4 + head] = pd; }
  }
}

// ---------------- layer1 edge passes ----------------
__global__ void k_emax1(const int* __restrict__ src, const int* __restrict__ dst,
                        const float* __restrict__ es, const float* __restrict__ ed,
                        float* __restrict__ emax, int E) {
  int stride = gridDim.x * blockDim.x;
  for (int i = blockIdx.x*blockDim.x + threadIdx.x; i < E; i += stride) {
    int s = src[i], d = dst[i];
    #pragma unroll
    for (int h = 0; h < 4; ++h) {
      float e = lrelu02(es[s*4+h] + ed[d*4+h]);
      atomicMaxF(&emax[d*4+h], e);
    }
  }
}

__global__ void k_denom1(const int* __restrict__ src, const int* __restrict__ dst,
                         const float* __restrict__ es, const float* __restrict__ ed,
                         const float* __restrict__ emax, float* __restrict__ denom, int E) {
  int stride = gridDim.x * blockDim.x;
  for (int i = blockIdx.x*blockDim.x + threadIdx.x; i < E; i += stride) {
    int s = src[i], d = dst[i];
    #pragma unroll
    for (int h = 0; h < 4; ++h) {
      float e = lrelu02(es[s*4+h] + ed[d*4+h]);
      atomicAdd(&denom[d*4+h], expf(e - emax[d*4+h]));
    }
  }
}

// one wave per edge: 64 lanes x float4 = 256 dims
__global__ void k_agg1(const int* __restrict__ src, const int* __restrict__ dst,
                       const float* __restrict__ es, const float* __restrict__ ed,
                       const float* __restrict__ emax, const float* __restrict__ denom,
                       const float* __restrict__ h1, float* __restrict__ agg, int E) {
  int tidg = blockIdx.x*blockDim.x + threadIdx.x;
  int wid = tidg >> 6, lane = tidg & 63;
  int nw = (gridDim.x * blockDim.x) >> 6;
  int h = lane >> 4;                            // head for dims [lane*4, lane*4+4)
  for (int e = wid; e < E; e += nw) {
    int s = src[e], d = dst[e];
    float ev = lrelu02(es[s*4+h] + ed[d*4+h]);
    float alpha = expf(ev - emax[d*4+h]) / (denom[d*4+h] + 1e-16f);
    float4 hv = *(const float4*)(h1 + (size_t)s*256 + lane*4);
    float* ag = agg + (size_t)d*256 + lane*4;
    atomicAdd(ag+0, alpha*hv.x);
    atomicAdd(ag+1, alpha*hv.y);
    atomicAdd(ag+2, alpha*hv.z);
    atomicAdd(ag+3, alpha*hv.w);
  }
}

// ------------- t2 = logmap0(expmap0(agg1)), rows of 256 (wave per row) -------------
__global__ void k_exp_log(const float* __restrict__ agg1, float* __restrict__ t2, int N) {
  int tidg = blockIdx.x*blockDim.x + threadIdx.x;
  int wid = tidg >> 6, lane = tidg & 63;
  int nw = (gridDim.x * blockDim.x) >> 6;
  for (int row = wid; row < N; row += nw) {
    float4 v = *(const float4*)(agg1 + (size_t)row*256 + lane*4);
    float ss = v.x*v.x + v.y*v.y + v.z*v.z + v.w*v.w;
    #pragma unroll
    for (int o = 32; o; o >>= 1) ss += __shfl_xor(ss, o);
    float n  = fmaxf(sqrtf(ss), EPSF);
    float s1 = tanhf(n) / n;                    // expmap0 scale
    float n2 = fmaxf(s1 * n, EPSF);             // norm after expmap (= tanh(n))
    float nc = fminf(n2, 1.f - 1e-5f);
    float s2 = atanhf(nc) / n2;                 // logmap0 scale
    float sc = s1 * s2;
    *(float4*)(t2 + (size_t)row*256 + lane*4) =
        make_float4(v.x*sc, v.y*sc, v.z*sc, v.w*sc);
  }
}

// ------------- layer2: t2 [N,256] @ W2 [256,64] -> h2 [N,64]; es2/ed2 [N] -------------
__global__ __launch_bounds__(256) void k_gemm2(
    const float* __restrict__ t2, const float* __restrict__ W2,
    const float* __restrict__ a_src, const float* __restrict__ a_dst,
    float* __restrict__ h2, float* __restrict__ es, float* __restrict__ ed, int N) {
  __shared__ float tile[16*256];
  const int tid = threadIdx.x;
  const int block0 = blockIdx.x * 16;
  int validf4 = (block0 < N ? ((N - block0 < 16) ? (N - block0) : 16) : 0) * 64;
  const float4* srcp = (const float4*)(t2 + (size_t)block0 * 256);
  for (int i = tid; i < 1024; i += 256) {
    float4 v = (i < validf4) ? srcp[i] : make_float4(0,0,0,0);
    ((float4*)tile)[i] = v;
  }
  __syncthreads();
  const int j = tid & 63, w = tid >> 6;         // wave w owns rows w*4..w*4+3
  float acc[4] = {0,0,0,0};
  const float* trow = &tile[(w*4)*256];
  for (int k = 0; k < 256; k += 4) {
    float w0 = W2[(size_t)(k+0)*64 + j];
    float w1 = W2[(size_t)(k+1)*64 + j];
    float w2v = W2[(size_t)(k+2)*64 + j];
    float w3 = W2[(size_t)(k+3)*64 + j];
    #pragma unroll
    for (int rr = 0; rr < 4; ++rr) {
      float4 tv = *(const float4*)&trow[rr*256 + k];
      acc[rr] += w0*tv.x + w1*tv.y + w2v*tv.z + w3*tv.w;
    }
  }
  const float as = a_src[j], ad = a_dst[j];
  #pragma unroll
  for (int rr = 0; rr < 4; ++rr) {
    int row = block0 + w*4 + rr;
    if (row < N) {
      float hv = acc[rr];
      h2[(size_t)row*64 + j] = hv;
      float ps = hv*as, pd = hv*ad;
      #pragma unroll
      for (int o = 32; o; o >>= 1) { ps += __shfl_xor(ps,o); pd += __shfl_xor(pd,o); }
      if (j == 0) { es[row] = ps; ed[row] = pd; }
    }
  }
}

// ---------------- layer2 edge passes (H=1) ----------------
__global__ void k_emax2(const int* __restrict__ src, const int* __restrict__ dst,
                        const float* __restrict__ es, const float* __restrict__ ed,
                        float* __restrict__ emax, int E) {
  int stride = gridDim.x * blockDim.x;
  for (int i = blockIdx.x*blockDim.x + threadIdx.x; i < E; i += stride) {
    float e = lrelu02(es[src[i]] + ed[dst[i]]);
    atomicMaxF(&emax[dst[i]], e);
  }
}

__global__ void k_denom2(const int* __restrict__ src, const int* __restrict__ dst,
                         const float* __restrict__ es, const float* __restrict__ ed,
                         const float* __restrict__ emax, float* __restrict__ denom, int E) {
  int stride = gridDim.x * blockDim.x;
  for (int i = blockIdx.x*blockDim.x + threadIdx.x; i < E; i += stride) {
    int d = dst[i];
    float e = lrelu02(es[src[i]] + ed[d]);
    atomicAdd(&denom[d], expf(e - emax[d]));
  }
}

// 16 lanes per edge: 16 x float4 = 64 dims
__global__ void k_agg2(const int* __restrict__ src, const int* __restrict__ dst,
                       const float* __restrict__ es, const float* __restrict__ ed,
                       const float* __restrict__ emax, const float* __restrict__ denom,
                       const float* __restrict__ h2, float* __restrict__ agg, int E) {
  int tidg = blockIdx.x*blockDim.x + threadIdx.x;
  int grp = tidg >> 4, l = tidg & 15;
  int ng = (gridDim.x * blockDim.x) >> 4;
  for (int e = grp; e < E; e += ng) {
    int s = src[e], d = dst[e];
    float ev = lrelu02(es[s] + ed[d]);
    float alpha = expf(ev - emax[d]) / (denom[d] + 1e-16f);
    float4 hv = *(const float4*)(h2 + (size_t)s*64 + l*4);
    float* ag = agg + (size_t)d*64 + l*4;
    atomicAdd(ag+0, alpha*hv.x);
    atomicAdd(ag+1, alpha*hv.y);
    atomicAdd(ag+2, alpha*hv.z);
    atomicAdd(ag+3, alpha*hv.w);
  }
}

// ------------- out = expmap0(agg2), rows of 64 (wave per row) -------------
__global__ void k_out(const float* __restrict__ agg2, float* __restrict__ out, int N) {
  int tidg = blockIdx.x*blockDim.x + threadIdx.x;
  int wid = tidg >> 6, lane = tidg & 63;
  int nw = (gridDim.x * blockDim.x) >> 6;
  for (int row = wid; row < N; row += nw) {
    float v = agg2[(size_t)row*64 + lane];
    float ss = v*v;
    #pragma unroll
    for (int o = 32; o; o >>= 1) ss += __shfl_xor(ss, o);
    float n  = fmaxf(sqrtf(ss), EPSF);
    float sc = tanhf(n) / n;
    out[(size_t)row*64 + lane] = v * sc;
  }
}

extern "C" void kernel_launch(void* const* d_in, const int* in_sizes, int n_in,
                              void* d_out, int out_size, void* d_ws, size_t ws_size,
                              hipStream_t stream) {
  const float* x      = (const float*)d_in[0];
  const float* W1     = (const float*)d_in[1];
  const float* a_src1 = (const float*)d_in[2];
  const float* a_dst1 = (const float*)d_in[3];
  const float* W2     = (const float*)d_in[4];
  const float* a_src2 = (const float*)d_in[5];
  const float* a_dst2 = (const float*)d_in[6];
  const int*   ei0    = (const int*)d_in[7];
  const int*   ei1    = (const int*)d_in[8];
  const int N  = in_sizes[0] / 128;
  const int E0 = in_sizes[7] / 2;
  const int E1 = in_sizes[8] / 2;
  const int* src0 = ei0;  const int* dst0 = ei0 + E0;
  const int* src1 = ei1;  const int* dst1 = ei1 + E1;
  float* out = (float*)d_out;

  float* ws = (float*)d_ws;
  size_t o = 0;
  float* h1    = ws + o; o += (size_t)N*256;   // reused as t2 after k_exp_log
  float* agg1  = ws + o; o += (size_t)N*256;
  float* h2    = ws + o; o += (size_t)N*64;
  float* agg2  = ws + o; o += (size_t)N*64;
  float* es1   = ws + o; o += (size_t)N*4;
  float* ed1   = ws + o; o += (size_t)N*4;
  float* emax1 = ws + o; o += (size_t)N*4;
  float* denom1= ws + o; o += (size_t)N*4;
  float* es2   = ws + o; o += (size_t)N;
  float* ed2   = ws + o; o += (size_t)N;
  float* emax2 = ws + o; o += (size_t)N;
  float* denom2= ws + o; o += (size_t)N;

  dim3 blk(256);
  k_init  <<<2048, blk, 0, stream>>>(agg1, agg2, denom1, denom2, emax1, emax2, N);
  k_gemm1 <<<(N+7)/8, blk, 0, stream>>>(x, W1, a_src1, a_dst1, h1, es1, ed1, N);
  k_emax1 <<<2048, blk, 0, stream>>>(src0, dst0, es1, ed1, emax1, E0);
  k_denom1<<<2048, blk, 0, stream>>>(src0, dst0, es1, ed1, emax1, denom1, E0);
  k_agg1  <<<2048, blk, 0, stream>>>(src0, dst0, es1, ed1, emax1, denom1, h1, agg1, E0);
  k_exp_log<<<2048, blk, 0, stream>>>(agg1, h1 /*t2*/, N);
  k_gemm2 <<<(N+15)/16, blk, 0, stream>>>(h1, W2, a_src2, a_dst2, h2, es2, ed2, N);
  k_emax2 <<<2048, blk, 0, stream>>>(src1, dst1, es2, ed2, emax2, E1);
  k_denom2<<<2048, blk, 0, stream>>>(src1, dst1, es2, ed2, emax2, denom2, E1);
  k_agg2  <<<2048, blk, 0, stream>>>(src1, dst1, es2, ed2, emax2, denom2, h2, agg2, E1);
  k_out   <<<2048, blk, 0, stream>>>(agg2, out, N);
}

// Round 2
// 775.762 us; speedup vs baseline: 5.0839x; 5.0839x over previous
//
#include <hip/hip_runtime.h>

#define EPSF 1e-7f

__device__ __forceinline__ float lrelu02(float x){ return x > 0.f ? x : 0.2f*x; }

// ---------------- CSR build ----------------
__global__ void k_zero(int* __restrict__ cnt0, int* __restrict__ cnt1, int N) {
  int stride = gridDim.x * blockDim.x;
  for (int i = blockIdx.x*blockDim.x + threadIdx.x; i < N; i += stride) {
    cnt0[i] = 0; cnt1[i] = 0;
  }
}

__global__ void k_hist(const int* __restrict__ dst0, int* __restrict__ cnt0, int E0,
                       const int* __restrict__ dst1, int* __restrict__ cnt1, int E1) {
  int stride = gridDim.x * blockDim.x;
  int tid = blockIdx.x*blockDim.x + threadIdx.x;
  for (int i = tid; i < E0; i += stride) atomicAdd(&cnt0[dst0[i]], 1);
  for (int i = tid; i < E1; i += stride) atomicAdd(&cnt1[dst1[i]], 1);
}

// single block, 1024 threads: exclusive scan of cnt -> rowptr[0..n], cursor=rowptr
__global__ __launch_bounds__(1024) void k_scan(const int* __restrict__ cnt,
                                               int* __restrict__ rowptr,
                                               int* __restrict__ cursor, int n) {
  __shared__ int wtot[16];
  const int tid = threadIdx.x;
  const int per = (n + 1023) / 1024;
  const int b = tid * per;
  const int e = min(b + per, n);
  int s = 0;
  for (int i = b; i < e; ++i) s += cnt[i];
  // inclusive scan of s over 1024 threads
  const int lane = tid & 63, w = tid >> 6;
  int v = s;
  #pragma unroll
  for (int o = 1; o < 64; o <<= 1) { int t = __shfl_up(v, o); if (lane >= o) v += t; }
  if (lane == 63) wtot[w] = v;
  __syncthreads();
  if (w == 0 && lane < 16) {
    int t = wtot[lane];
    #pragma unroll
    for (int o = 1; o < 16; o <<= 1) { int u = __shfl_up(t, o); if (lane >= o) t += u; }
    wtot[lane] = t;
  }
  __syncthreads();
  int base = (w > 0 ? wtot[w-1] : 0) + (v - s);   // exclusive prefix for this thread
  for (int i = b; i < e; ++i) {
    rowptr[i] = base; cursor[i] = base; base += cnt[i];
  }
  if (b < n && e == n) rowptr[n] = base;          // total
}

__global__ void k_scatter(const int* __restrict__ src, const int* __restrict__ dst,
                          int* __restrict__ cursor, int* __restrict__ csrc, int E) {
  int stride = gridDim.x * blockDim.x;
  for (int i = blockIdx.x*blockDim.x + threadIdx.x; i < E; i += stride) {
    int pos = atomicAdd(&cursor[dst[i]], 1);
    csrc[pos] = src[i];
  }
}

// ------------- layer1: logmap0(x) @ W1 -> h1 [N,256]; es1/ed1 [N,4] -------------
__global__ __launch_bounds__(256) void k_gemm1(
    const float* __restrict__ x, const float* __restrict__ W1,
    const float* __restrict__ a_src, const float* __restrict__ a_dst,
    float* __restrict__ h1, float* __restrict__ es, float* __restrict__ ed, int N) {
  __shared__ float t[8][128];
  const int tid = threadIdx.x;
  const int block0 = blockIdx.x * 8;
  {
    const int r = tid >> 5, c = (tid & 31) * 4;
    const int row = block0 + r;
    float4 v = make_float4(0.f,0.f,0.f,0.f);
    if (row < N) v = *(const float4*)(x + (size_t)row*128 + c);
    float ss = v.x*v.x + v.y*v.y + v.z*v.z + v.w*v.w;
    #pragma unroll
    for (int o = 16; o; o >>= 1) ss += __shfl_xor(ss, o);
    float n  = fmaxf(sqrtf(ss), EPSF);
    float nc = fminf(n, 1.f - 1e-5f);
    float sc = atanhf(nc) / n;                 // logmap0 scale
    *(float4*)&t[r][c] = make_float4(v.x*sc, v.y*sc, v.z*sc, v.w*sc);
  }
  __syncthreads();

  const int j = tid;                            // output column 0..255
  float acc[8] = {0,0,0,0,0,0,0,0};
  for (int k = 0; k < 128; k += 4) {
    float w0 = W1[(size_t)(k+0)*256 + j];
    float w1 = W1[(size_t)(k+1)*256 + j];
    float w2 = W1[(size_t)(k+2)*256 + j];
    float w3 = W1[(size_t)(k+3)*256 + j];
    #pragma unroll
    for (int rr = 0; rr < 8; ++rr) {
      float4 tv = *(const float4*)&t[rr][k];
      acc[rr] += w0*tv.x + w1*tv.y + w2*tv.z + w3*tv.w;
    }
  }
  const int head = tid >> 6, lane = tid & 63;   // wave == head
  const float as = a_src[head*64 + lane];
  const float ad = a_dst[head*64 + lane];
  #pragma unroll
  for (int rr = 0; rr < 8; ++rr) {
    int rown = block0 + rr;
    if (rown >= N) break;
    float hv = acc[rr];
    h1[(size_t)rown*256 + j] = hv;
    float ps = hv * as, pd = hv * ad;
    #pragma unroll
    for (int o = 32; o; o >>= 1) { ps += __shfl_xor(ps, o); pd += __shfl_xor(pd, o); }
    if (lane == 0) { es[rown*4 + head] = ps; ed[rown*4 + head] = pd; }
  }
}

// ------------- layer1 aggregation (CSR, wave per dst) + fused expmap0/logmap0 -------------
__global__ void k_agg1_csr(const int* __restrict__ rowptr, const int* __restrict__ csrc,
                           const float* __restrict__ es, const float* __restrict__ ed,
                           const float* __restrict__ h1, float* __restrict__ t2, int N) {
  int tidg = blockIdx.x*blockDim.x + threadIdx.x;
  int wid = tidg >> 6, lane = tidg & 63;
  int nw = (gridDim.x * blockDim.x) >> 6;
  const int h = lane >> 4;                      // head for dims [lane*4, lane*4+4)
  const int sub = lane & 15;
  for (int d = wid; d < N; d += nw) {
    const int beg = rowptr[d], end = rowptr[d+1];
    const float edv = ed[d*4 + h];
    // pass 1: per-head max, edges split over the 16 lanes of the head group
    float m = -__builtin_inff();
    for (int k = beg + sub; k < end; k += 16) {
      int s = csrc[k];
      m = fmaxf(m, lrelu02(es[s*4 + h] + edv));
    }
    #pragma unroll
    for (int o = 1; o < 16; o <<= 1) m = fmaxf(m, __shfl_xor(m, o));
    // pass 2: weighted accumulation + denom (denom identical across head group)
    float4 acc = make_float4(0.f,0.f,0.f,0.f);
    float wsum = 0.f;
    for (int k = beg; k < end; ++k) {
      int s = csrc[k];
      float e = lrelu02(es[s*4 + h] + edv);
      float w = expf(e - m);
      wsum += w;
      float4 hv = *(const float4*)(h1 + (size_t)s*256 + lane*4);
      acc.x += w*hv.x; acc.y += w*hv.y; acc.z += w*hv.z; acc.w += w*hv.w;
    }
    float inv = 1.f / (wsum + 1e-16f);
    float ax = acc.x*inv, ay = acc.y*inv, az = acc.z*inv, aw = acc.w*inv;
    // fused t2 = logmap0(expmap0(agg)) over the 256-dim row
    float ss = ax*ax + ay*ay + az*az + aw*aw;
    #pragma unroll
    for (int o = 32; o; o >>= 1) ss += __shfl_xor(ss, o);
    float n  = fmaxf(sqrtf(ss), EPSF);
    float s1 = tanhf(n) / n;                    // expmap0 scale
    float n2 = fmaxf(s1 * n, EPSF);             // = tanh(n) (clamped)
    float nc = fminf(n2, 1.f - 1e-5f);
    float sc = s1 * atanhf(nc) / n2;
    *(float4*)(t2 + (size_t)d*256 + lane*4) =
        make_float4(ax*sc, ay*sc, az*sc, aw*sc);
  }
}

// ------------- layer2: t2 [N,256] @ W2 [256,64] -> h2 [N,64]; es2/ed2 [N] -------------
__global__ __launch_bounds__(256) void k_gemm2(
    const float* __restrict__ t2, const float* __restrict__ W2,
    const float* __restrict__ a_src, const float* __restrict__ a_dst,
    float* __restrict__ h2, float* __restrict__ es, float* __restrict__ ed, int N) {
  __shared__ float tile[16*256];
  const int tid = threadIdx.x;
  const int block0 = blockIdx.x * 16;
  int validf4 = (block0 < N ? ((N - block0 < 16) ? (N - block0) : 16) : 0) * 64;
  const float4* srcp = (const float4*)(t2 + (size_t)block0 * 256);
  for (int i = tid; i < 1024; i += 256) {
    float4 v = (i < validf4) ? srcp[i] : make_float4(0,0,0,0);
    ((float4*)tile)[i] = v;
  }
  __syncthreads();
  const int j = tid & 63, w = tid >> 6;
  float acc[4] = {0,0,0,0};
  const float* trow = &tile[(w*4)*256];
  for (int k = 0; k < 256; k += 4) {
    float w0 = W2[(size_t)(k+0)*64 + j];
    float w1 = W2[(size_t)(k+1)*64 + j];
    float w2v = W2[(size_t)(k+2)*64 + j];
    float w3 = W2[(size_t)(k+3)*64 + j];
    #pragma unroll
    for (int rr = 0; rr < 4; ++rr) {
      float4 tv = *(const float4*)&trow[rr*256 + k];
      acc[rr] += w0*tv.x + w1*tv.y + w2v*tv.z + w3*tv.w;
    }
  }
  const float as = a_src[j], ad = a_dst[j];
  #pragma unroll
  for (int rr = 0; rr < 4; ++rr) {
    int row = block0 + w*4 + rr;
    if (row < N) {
      float hv = acc[rr];
      h2[(size_t)row*64 + j] = hv;
      float ps = hv*as, pd = hv*ad;
      #pragma unroll
      for (int o = 32; o; o >>= 1) { ps += __shfl_xor(ps,o); pd += __shfl_xor(pd,o); }
      if (j == 0) { es[row] = ps; ed[row] = pd; }
    }
  }
}

// ------------- layer2 aggregation (CSR, wave per dst) + fused expmap0 -------------
__global__ void k_agg2_csr(const int* __restrict__ rowptr, const int* __restrict__ csrc,
                           const float* __restrict__ es, const float* __restrict__ ed,
                           const float* __restrict__ h2, float* __restrict__ out, int N) {
  int tidg = blockIdx.x*blockDim.x + threadIdx.x;
  int wid = tidg >> 6, lane = tidg & 63;
  int nw = (gridDim.x * blockDim.x) >> 6;
  for (int d = wid; d < N; d += nw) {
    const int beg = rowptr[d], end = rowptr[d+1];
    const float edv = ed[d];
    float m = -__builtin_inff();
    for (int k = beg + lane; k < end; k += 64) {
      m = fmaxf(m, lrelu02(es[csrc[k]] + edv));
    }
    #pragma unroll
    for (int o = 32; o; o >>= 1) m = fmaxf(m, __shfl_xor(m, o));
    float acc = 0.f, wsum = 0.f;
    for (int k = beg; k < end; ++k) {
      int s = csrc[k];
      float w = expf(lrelu02(es[s] + edv) - m);
      wsum += w;
      acc += w * h2[(size_t)s*64 + lane];
    }
    float a = acc / (wsum + 1e-16f);
    float ss = a*a;
    #pragma unroll
    for (int o = 32; o; o >>= 1) ss += __shfl_xor(ss, o);
    float n  = fmaxf(sqrtf(ss), EPSF);
    float sc = tanhf(n) / n;                    // expmap0 scale
    out[(size_t)d*64 + lane] = a * sc;
  }
}

extern "C" void kernel_launch(void* const* d_in, const int* in_sizes, int n_in,
                              void* d_out, int out_size, void* d_ws, size_t ws_size,
                              hipStream_t stream) {
  const float* x      = (const float*)d_in[0];
  const float* W1     = (const float*)d_in[1];
  const float* a_src1 = (const float*)d_in[2];
  const float* a_dst1 = (const float*)d_in[3];
  const float* W2     = (const float*)d_in[4];
  const float* a_src2 = (const float*)d_in[5];
  const float* a_dst2 = (const float*)d_in[6];
  const int*   ei0    = (const int*)d_in[7];
  const int*   ei1    = (const int*)d_in[8];
  const int N  = in_sizes[0] / 128;
  const int E0 = in_sizes[7] / 2;
  const int E1 = in_sizes[8] / 2;
  const int* src0 = ei0;  const int* dst0 = ei0 + E0;
  const int* src1 = ei1;  const int* dst1 = ei1 + E1;
  float* out = (float*)d_out;

  float* ws = (float*)d_ws;
  size_t o = 0;
  float* h1    = ws + o; o += (size_t)N*256;
  float* t2    = ws + o; o += (size_t)N*256;
  float* h2    = ws + o; o += (size_t)N*64;
  float* es1   = ws + o; o += (size_t)N*4;
  float* ed1   = ws + o; o += (size_t)N*4;
  float* es2   = ws + o; o += (size_t)N;
  float* ed2   = ws + o; o += (size_t)N;
  int* iws = (int*)(ws + o);
  size_t io = 0;
  int* cnt0    = iws + io; io += N;
  int* rowptr0 = iws + io; io += N + 1;
  int* cursor0 = iws + io; io += N;
  int* cnt1    = iws + io; io += N;
  int* rowptr1 = iws + io; io += N + 1;
  int* cursor1 = iws + io; io += N;
  int* csrc0   = iws + io; io += E0;
  int* csrc1   = iws + io; io += E1;

  dim3 blk(256);
  // CSR build for both graphs
  k_zero   <<<256, blk, 0, stream>>>(cnt0, cnt1, N);
  k_hist   <<<1024, blk, 0, stream>>>(dst0, cnt0, E0, dst1, cnt1, E1);
  k_scan   <<<1, 1024, 0, stream>>>(cnt0, rowptr0, cursor0, N);
  k_scan   <<<1, 1024, 0, stream>>>(cnt1, rowptr1, cursor1, N);
  k_scatter<<<1024, blk, 0, stream>>>(src0, dst0, cursor0, csrc0, E0);
  k_scatter<<<1024, blk, 0, stream>>>(src1, dst1, cursor1, csrc1, E1);
  // layer 1
  k_gemm1   <<<(N+7)/8, blk, 0, stream>>>(x, W1, a_src1, a_dst1, h1, es1, ed1, N);
  k_agg1_csr<<<2048, blk, 0, stream>>>(rowptr0, csrc0, es1, ed1, h1, t2, N);
  // layer 2
  k_gemm2   <<<(N+15)/16, blk, 0, stream>>>(t2, W2, a_src2, a_dst2, h2, es2, ed2, N);
  k_agg2_csr<<<2048, blk, 0, stream>>>(rowptr1, csrc1, es2, ed2, h2, out, N);
}

// Round 3
// 646.781 us; speedup vs baseline: 6.0977x; 1.1994x over previous
//
#include <hip/hip_runtime.h>

#define EPSF 1e-7f

typedef __attribute__((ext_vector_type(4))) _Float16 half4;

__device__ __forceinline__ float lrelu02(float x){ return x > 0.f ? x : 0.2f*x; }

// ---------------- CSR build ----------------
__global__ void k_zero(int* __restrict__ cnt0, int* __restrict__ cnt1, int N) {
  int stride = gridDim.x * blockDim.x;
  for (int i = blockIdx.x*blockDim.x + threadIdx.x; i < N; i += stride) {
    cnt0[i] = 0; cnt1[i] = 0;
  }
}

__global__ void k_hist(const int* __restrict__ dst0, int* __restrict__ cnt0, int E0,
                       const int* __restrict__ dst1, int* __restrict__ cnt1, int E1) {
  int stride = gridDim.x * blockDim.x;
  int tid = blockIdx.x*blockDim.x + threadIdx.x;
  for (int i = tid; i < E0; i += stride) atomicAdd(&cnt0[dst0[i]], 1);
  for (int i = tid; i < E1; i += stride) atomicAdd(&cnt1[dst1[i]], 1);
}

// 2 blocks, 1024 threads each: exclusive scan of cnt -> rowptr[0..n], cursor=rowptr
__global__ __launch_bounds__(1024) void k_scan2(
    int* __restrict__ cnt0, int* __restrict__ rowptr0, int* __restrict__ cursor0,
    int* __restrict__ cnt1, int* __restrict__ rowptr1, int* __restrict__ cursor1, int n) {
  const int* cnt   = blockIdx.x ? cnt1    : cnt0;
  int* rowptr      = blockIdx.x ? rowptr1 : rowptr0;
  int* cursor      = blockIdx.x ? cursor1 : cursor0;
  __shared__ int wtot[16];
  const int tid = threadIdx.x;
  const int per = (n + 1023) / 1024;
  const int b = tid * per;
  const int e = min(b + per, n);
  int s = 0;
  for (int i = b; i < e; ++i) s += cnt[i];
  const int lane = tid & 63, w = tid >> 6;
  int v = s;
  #pragma unroll
  for (int o = 1; o < 64; o <<= 1) { int t = __shfl_up(v, o); if (lane >= o) v += t; }
  if (lane == 63) wtot[w] = v;
  __syncthreads();
  if (w == 0 && lane < 16) {
    int t = wtot[lane];
    #pragma unroll
    for (int o = 1; o < 16; o <<= 1) { int u = __shfl_up(t, o); if (lane >= o) t += u; }
    wtot[lane] = t;
  }
  __syncthreads();
  int base = (w > 0 ? wtot[w-1] : 0) + (v - s);
  for (int i = b; i < e; ++i) {
    rowptr[i] = base; cursor[i] = base; base += cnt[i];
  }
  if (b < n && e == n) rowptr[n] = base;
}

__global__ void k_scatter2(const int* __restrict__ src0, const int* __restrict__ dst0,
                           int* __restrict__ cursor0, int* __restrict__ csrc0, int E0,
                           const int* __restrict__ src1, const int* __restrict__ dst1,
                           int* __restrict__ cursor1, int* __restrict__ csrc1, int E1) {
  int stride = gridDim.x * blockDim.x;
  int tid = blockIdx.x*blockDim.x + threadIdx.x;
  for (int i = tid; i < E0; i += stride) {
    int pos = atomicAdd(&cursor0[dst0[i]], 1);
    csrc0[pos] = src0[i];
  }
  for (int i = tid; i < E1; i += stride) {
    int pos = atomicAdd(&cursor1[dst1[i]], 1);
    csrc1[pos] = src1[i];
  }
}

// ------------- layer1: logmap0(x) @ W1 -> h1 (fp16) [N,256]; es1/ed1 [N,4] -------------
__global__ __launch_bounds__(256) void k_gemm1(
    const float* __restrict__ x, const float* __restrict__ W1,
    const float* __restrict__ a_src, const float* __restrict__ a_dst,
    _Float16* __restrict__ h1h, float* __restrict__ es, float* __restrict__ ed, int N) {
  __shared__ float t[32][128];          // 16 KB
  const int tid = threadIdx.x;
  const int block0 = blockIdx.x * 32;
  // load 32 rows x 128 in 4 passes: 32 lanes/row, float4 each, logmap0 scale per row
  #pragma unroll
  for (int p = 0; p < 4; ++p) {
    const int r = (tid >> 5) + p*8, c = (tid & 31) * 4;
    const int row = block0 + r;
    float4 v = make_float4(0.f,0.f,0.f,0.f);
    if (row < N) v = *(const float4*)(x + (size_t)row*128 + c);
    float ss = v.x*v.x + v.y*v.y + v.z*v.z + v.w*v.w;
    #pragma unroll
    for (int o = 16; o; o >>= 1) ss += __shfl_xor(ss, o);
    float n  = fmaxf(sqrtf(ss), EPSF);
    float nc = fminf(n, 1.f - 1e-5f);
    float sc = atanhf(nc) / n;                 // logmap0 scale
    *(float4*)&t[r][c] = make_float4(v.x*sc, v.y*sc, v.z*sc, v.w*sc);
  }
  __syncthreads();

  const int j = tid;                            // output column 0..255
  float acc[32];
  #pragma unroll
  for (int rr = 0; rr < 32; ++rr) acc[rr] = 0.f;
  for (int k = 0; k < 128; k += 4) {
    float w0 = W1[(size_t)(k+0)*256 + j];
    float w1 = W1[(size_t)(k+1)*256 + j];
    float w2 = W1[(size_t)(k+2)*256 + j];
    float w3 = W1[(size_t)(k+3)*256 + j];
    #pragma unroll
    for (int rr = 0; rr < 32; ++rr) {
      float4 tv = *(const float4*)&t[rr][k];   // broadcast across wave
      acc[rr] += w0*tv.x + w1*tv.y + w2*tv.z + w3*tv.w;
    }
  }
  const int head = tid >> 6, lane = tid & 63;   // wave == head
  const float as = a_src[head*64 + lane];
  const float ad = a_dst[head*64 + lane];
  #pragma unroll
  for (int rr = 0; rr < 32; ++rr) {
    int rown = block0 + rr;
    if (rown >= N) break;                       // uniform per block
    float hv = acc[rr];
    h1h[(size_t)rown*256 + j] = (_Float16)hv;
    float ps = hv * as, pd = hv * ad;
    #pragma unroll
    for (int o = 32; o; o >>= 1) { ps += __shfl_xor(ps, o); pd += __shfl_xor(pd, o); }
    if (lane == 0) { es[rown*4 + head] = ps; ed[rown*4 + head] = pd; }
  }
}

// ------------- layer1 aggregation (CSR, wave per dst, single pass, no max)
//               + fused expmap0/logmap0 -> t2 fp32 -------------
__global__ void k_agg1_csr(const int* __restrict__ rowptr, const int* __restrict__ csrc,
                           const float* __restrict__ es, const float* __restrict__ ed,
                           const _Float16* __restrict__ h1h, float* __restrict__ t2, int N) {
  int tidg = blockIdx.x*blockDim.x + threadIdx.x;
  int wid = tidg >> 6, lane = tidg & 63;
  int nw = (gridDim.x * blockDim.x) >> 6;
  const int h = lane >> 4;                      // head for dims [lane*4, lane*4+4)
  for (int d = wid; d < N; d += nw) {
    const int beg = rowptr[d], end = rowptr[d+1];
    const float edv = ed[d*4 + h];
    float4 acc = make_float4(0.f,0.f,0.f,0.f);
    float wsum = 0.f;
    for (int k = beg; k < end; ++k) {
      int s = csrc[k];
      float e = lrelu02(es[s*4 + h] + edv);
      float w = __expf(e);                      // shift-invariant: max dropped
      wsum += w;
      half4 hv = *(const half4*)(h1h + (size_t)s*256 + lane*4);
      acc.x += w*(float)hv.x; acc.y += w*(float)hv.y;
      acc.z += w*(float)hv.z; acc.w += w*(float)hv.w;
    }
    float inv = 1.f / (wsum + 1e-16f);
    float ax = acc.x*inv, ay = acc.y*inv, az = acc.z*inv, aw = acc.w*inv;
    // fused t2 = logmap0(expmap0(agg)) over the 256-dim row
    float ss = ax*ax + ay*ay + az*az + aw*aw;
    #pragma unroll
    for (int o = 32; o; o >>= 1) ss += __shfl_xor(ss, o);
    float n  = fmaxf(sqrtf(ss), EPSF);
    float s1 = tanhf(n) / n;                    // expmap0 scale
    float n2 = fmaxf(s1 * n, EPSF);             // = tanh(n), clamped
    float nc = fminf(n2, 1.f - 1e-5f);
    float sc = s1 * atanhf(nc) / n2;
    *(float4*)(t2 + (size_t)d*256 + lane*4) =
        make_float4(ax*sc, ay*sc, az*sc, aw*sc);
  }
}

// ------------- layer2: t2 [N,256] @ W2 [256,64] -> h2 (fp16) [N,64]; es2/ed2 [N] -------------
__global__ __launch_bounds__(256) void k_gemm2(
    const float* __restrict__ t2, const float* __restrict__ W2,
    const float* __restrict__ a_src, const float* __restrict__ a_dst,
    _Float16* __restrict__ h2h, float* __restrict__ es, float* __restrict__ ed, int N) {
  __shared__ float tile[32*256];                // 32 KB
  const int tid = threadIdx.x;
  const int block0 = blockIdx.x * 32;
  int validf4 = (block0 < N ? ((N - block0 < 32) ? (N - block0) : 32) : 0) * 64;
  const float4* srcp = (const float4*)(t2 + (size_t)block0 * 256);
  for (int i = tid; i < 2048; i += 256) {
    float4 v = (i < validf4) ? srcp[i] : make_float4(0,0,0,0);
    ((float4*)tile)[i] = v;
  }
  __syncthreads();
  const int j = tid & 63, g = tid >> 6;         // group g owns rows g*8..g*8+7
  float acc[8];
  #pragma unroll
  for (int rr = 0; rr < 8; ++rr) acc[rr] = 0.f;
  const float* trow = &tile[(g*8)*256];
  for (int k = 0; k < 256; k += 4) {
    float w0 = W2[(size_t)(k+0)*64 + j];
    float w1 = W2[(size_t)(k+1)*64 + j];
    float w2v = W2[(size_t)(k+2)*64 + j];
    float w3 = W2[(size_t)(k+3)*64 + j];
    #pragma unroll
    for (int rr = 0; rr < 8; ++rr) {
      float4 tv = *(const float4*)&trow[rr*256 + k];
      acc[rr] += w0*tv.x + w1*tv.y + w2v*tv.z + w3*tv.w;
    }
  }
  const float as = a_src[j], ad = a_dst[j];
  #pragma unroll
  for (int rr = 0; rr < 8; ++rr) {
    int row = block0 + g*8 + rr;
    if (row < N) {
      float hv = acc[rr];
      h2h[(size_t)row*64 + j] = (_Float16)hv;
      float ps = hv*as, pd = hv*ad;
      #pragma unroll
      for (int o = 32; o; o >>= 1) { ps += __shfl_xor(ps,o); pd += __shfl_xor(pd,o); }
      if (j == 0) { es[row] = ps; ed[row] = pd; }
    }
  }
}

// ------------- layer2 aggregation (CSR, wave per dst, single pass) + fused expmap0 -------------
__global__ void k_agg2_csr(const int* __restrict__ rowptr, const int* __restrict__ csrc,
                           const float* __restrict__ es, const float* __restrict__ ed,
                           const _Float16* __restrict__ h2h, float* __restrict__ out, int N) {
  int tidg = blockIdx.x*blockDim.x + threadIdx.x;
  int wid = tidg >> 6, lane = tidg & 63;
  int nw = (gridDim.x * blockDim.x) >> 6;
  for (int d = wid; d < N; d += nw) {
    const int beg = rowptr[d], end = rowptr[d+1];
    const float edv = ed[d];
    float acc = 0.f, wsum = 0.f;
    for (int k = beg; k < end; ++k) {
      int s = csrc[k];
      float w = __expf(lrelu02(es[s] + edv));
      wsum += w;
      acc += w * (float)h2h[(size_t)s*64 + lane];
    }
    float a = acc / (wsum + 1e-16f);
    float ss = a*a;
    #pragma unroll
    for (int o = 32; o; o >>= 1) ss += __shfl_xor(ss, o);
    float n  = fmaxf(sqrtf(ss), EPSF);
    float sc = tanhf(n) / n;                    // expmap0 scale
    out[(size_t)d*64 + lane] = a * sc;
  }
}

extern "C" void kernel_launch(void* const* d_in, const int* in_sizes, int n_in,
                              void* d_out, int out_size, void* d_ws, size_t ws_size,
                              hipStream_t stream) {
  const float* x      = (const float*)d_in[0];
  const float* W1     = (const float*)d_in[1];
  const float* a_src1 = (const float*)d_in[2];
  const float* a_dst1 = (const float*)d_in[3];
  const float* W2     = (const float*)d_in[4];
  const float* a_src2 = (const float*)d_in[5];
  const float* a_dst2 = (const float*)d_in[6];
  const int*   ei0    = (const int*)d_in[7];
  const int*   ei1    = (const int*)d_in[8];
  const int N  = in_sizes[0] / 128;
  const int E0 = in_sizes[7] / 2;
  const int E1 = in_sizes[8] / 2;
  const int* src0 = ei0;  const int* dst0 = ei0 + E0;
  const int* src1 = ei1;  const int* dst1 = ei1 + E1;
  float* out = (float*)d_out;

  float* ws = (float*)d_ws;
  size_t o = 0;
  float* t2    = ws + o; o += (size_t)N*256;
  float* es1   = ws + o; o += (size_t)N*4;
  float* ed1   = ws + o; o += (size_t)N*4;
  float* es2   = ws + o; o += (size_t)N;
  float* ed2   = ws + o; o += (size_t)N;
  _Float16* h1h = (_Float16*)(ws + o); o += (size_t)N*128;  // N*256 halves
  _Float16* h2h = (_Float16*)(ws + o); o += (size_t)N*32;   // N*64 halves
  int* iws = (int*)(ws + o);
  size_t io = 0;
  int* cnt0    = iws + io; io += N;
  int* rowptr0 = iws + io; io += N + 1;
  int* cursor0 = iws + io; io += N;
  int* cnt1    = iws + io; io += N;
  int* rowptr1 = iws + io; io += N + 1;
  int* cursor1 = iws + io; io += N;
  int* csrc0   = iws + io; io += E0;
  int* csrc1   = iws + io; io += E1;

  dim3 blk(256);
  // CSR build for both graphs
  k_zero    <<<256, blk, 0, stream>>>(cnt0, cnt1, N);
  k_hist    <<<1024, blk, 0, stream>>>(dst0, cnt0, E0, dst1, cnt1, E1);
  k_scan2   <<<2, 1024, 0, stream>>>(cnt0, rowptr0, cursor0, cnt1, rowptr1, cursor1, N);
  k_scatter2<<<1024, blk, 0, stream>>>(src0, dst0, cursor0, csrc0, E0,
                                       src1, dst1, cursor1, csrc1, E1);
  // layer 1
  k_gemm1   <<<(N+31)/32, blk, 0, stream>>>(x, W1, a_src1, a_dst1, h1h, es1, ed1, N);
  k_agg1_csr<<<2048, blk, 0, stream>>>(rowptr0, csrc0, es1, ed1, h1h, t2, N);
  // layer 2
  k_gemm2   <<<(N+31)/32, blk, 0, stream>>>(t2, W2, a_src2, a_dst2, h2h, es2, ed2, N);
  k_agg2_csr<<<2048, blk, 0, stream>>>(rowptr1, csrc1, es2, ed2, h2h, out, N);
}

// Round 6
// 476.204 us; speedup vs baseline: 8.2819x; 1.3582x over previous
//
#include <hip/hip_runtime.h>

#define EPSF 1e-7f
#define NBMAX 512   // max dst-buckets (ceil(N/128)); N=50000 -> 391

typedef __attribute__((ext_vector_type(4))) _Float16 half4;
typedef unsigned long long u64;

__device__ __forceinline__ float lrelu02(float x){ return x > 0.f ? x : 0.2f*x; }

// ---------------- CSR build ----------------
__global__ void k_zero(int* __restrict__ cnt0, int* __restrict__ cnt1, int N) {
  int stride = gridDim.x * blockDim.x;
  for (int i = blockIdx.x*blockDim.x + threadIdx.x; i < N; i += stride) {
    cnt0[i] = 0; cnt1[i] = 0;
  }
}

__global__ void k_hist(const int* __restrict__ dst0, int* __restrict__ cnt0, int E0,
                       const int* __restrict__ dst1, int* __restrict__ cnt1, int E1) {
  int stride = gridDim.x * blockDim.x;
  int tid = blockIdx.x*blockDim.x + threadIdx.x;
  for (int i = tid; i < E0; i += stride) atomicAdd(&cnt0[dst0[i]], 1);
  for (int i = tid; i < E1; i += stride) atomicAdd(&cnt1[dst1[i]], 1);
}

// 2 blocks, 1024 threads: exclusive scan of cnt -> rowptr[0..n]; bucket cursors
__global__ __launch_bounds__(1024) void k_scan2(
    int* __restrict__ cnt0, int* __restrict__ rowptr0, int* __restrict__ bcur0,
    int* __restrict__ cnt1, int* __restrict__ rowptr1, int* __restrict__ bcur1, int n) {
  const int* cnt   = blockIdx.x ? cnt1    : cnt0;
  int* rowptr      = blockIdx.x ? rowptr1 : rowptr0;
  int* bcur        = blockIdx.x ? bcur1   : bcur0;
  __shared__ int wtot[16];
  const int tid = threadIdx.x;
  const int per = (n + 1023) / 1024;
  const int b = tid * per;
  const int e = min(b + per, n);
  int s = 0;
  for (int i = b; i < e; ++i) s += cnt[i];
  const int lane = tid & 63, w = tid >> 6;
  int v = s;
  #pragma unroll
  for (int o = 1; o < 64; o <<= 1) { int t = __shfl_up(v, o); if (lane >= o) v += t; }
  if (lane == 63) wtot[w] = v;
  __syncthreads();
  if (w == 0 && lane < 16) {
    int t = wtot[lane];
    #pragma unroll
    for (int o = 1; o < 16; o <<= 1) { int u = __shfl_up(t, o); if (lane >= o) t += u; }
    wtot[lane] = t;
  }
  __syncthreads();
  int base = (w > 0 ? wtot[w-1] : 0) + (v - s);
  for (int i = b; i < e; ++i) {
    rowptr[i] = base;
    if ((i & 127) == 0) bcur[i >> 7] = base;   // bucket cursor start
    base += cnt[i];
  }
  if (b < n && e == n) rowptr[n] = base;
}

// pass A: bucket edges by dst>>7 into temp (packed (dst<<32)|src), runs block-clustered
__global__ __launch_bounds__(256) void k_bucketA(
    const int* __restrict__ src, const int* __restrict__ dst,
    int* __restrict__ bcur, u64* __restrict__ temp, int E, int nb) {
  __shared__ int hist[NBMAX];
  __shared__ int lbase[NBMAX];
  const int tid = threadIdx.x;
  const int chunk0 = blockIdx.x * 4096;
  const int e_end = min(chunk0 + 4096, E);
  for (int i = tid; i < nb; i += 256) hist[i] = 0;
  __syncthreads();
  for (int i = chunk0 + tid; i < e_end; i += 256)
    atomicAdd(&hist[dst[i] >> 7], 1);
  __syncthreads();
  for (int bn = tid; bn < nb; bn += 256) {
    int c = hist[bn];
    lbase[bn] = c ? atomicAdd(&bcur[bn], c) : 0;
    hist[bn] = 0;
  }
  __syncthreads();
  for (int i = chunk0 + tid; i < e_end; i += 256) {
    int d = dst[i];
    int bn = d >> 7;
    int off = atomicAdd(&hist[bn], 1);
    temp[(size_t)lbase[bn] + off] = ((u64)(unsigned)d << 32) | (unsigned)src[i];
  }
}

// pass B: within-bucket ordering -> csrc (one block per bucket; writes L2-local)
__global__ __launch_bounds__(256) void k_bucketB(
    const u64* __restrict__ temp, const int* __restrict__ rowptr,
    int* __restrict__ csrc, int N) {
  __shared__ int lcur[128];
  const int tid = threadIdx.x;
  const int d0 = blockIdx.x << 7;
  const int d1 = min(d0 + 128, N);
  for (int i = tid; i < d1 - d0; i += 256) lcur[i] = rowptr[d0 + i];
  __syncthreads();
  const int lo = rowptr[d0], hi = rowptr[d1];
  for (int k = lo + tid; k < hi; k += 256) {
    u64 p = temp[k];
    int d = (int)(p >> 32);
    int s = (int)(unsigned)p;
    int pos = atomicAdd(&lcur[d - d0], 1);
    csrc[pos] = s;
  }
}

// ------------- layer1: logmap0(x) @ W1 -> h1 (fp16) [N,256]; es1/ed1 [N,4] -------------
__global__ __launch_bounds__(256) void k_gemm1(
    const float* __restrict__ x, const float* __restrict__ W1,
    const float* __restrict__ a_src, const float* __restrict__ a_dst,
    _Float16* __restrict__ h1h, float* __restrict__ es, float* __restrict__ ed, int N) {
  __shared__ float t[32][128];          // 16 KB
  const int tid = threadIdx.x;
  const int block0 = blockIdx.x * 32;
  #pragma unroll
  for (int p = 0; p < 4; ++p) {
    const int r = (tid >> 5) + p*8, c = (tid & 31) * 4;
    const int row = block0 + r;
    float4 v = make_float4(0.f,0.f,0.f,0.f);
    if (row < N) v = *(const float4*)(x + (size_t)row*128 + c);
    float ss = v.x*v.x + v.y*v.y + v.z*v.z + v.w*v.w;
    #pragma unroll
    for (int o = 16; o; o >>= 1) ss += __shfl_xor(ss, o);
    float n  = fmaxf(sqrtf(ss), EPSF);
    float nc = fminf(n, 1.f - 1e-5f);
    float sc = atanhf(nc) / n;                 // logmap0 scale
    *(float4*)&t[r][c] = make_float4(v.x*sc, v.y*sc, v.z*sc, v.w*sc);
  }
  __syncthreads();

  const int j = tid;
  float acc[32];
  #pragma unroll
  for (int rr = 0; rr < 32; ++rr) acc[rr] = 0.f;
  for (int k = 0; k < 128; k += 4) {
    float w0 = W1[(size_t)(k+0)*256 + j];
    float w1 = W1[(size_t)(k+1)*256 + j];
    float w2 = W1[(size_t)(k+2)*256 + j];
    float w3 = W1[(size_t)(k+3)*256 + j];
    #pragma unroll
    for (int rr = 0; rr < 32; ++rr) {
      float4 tv = *(const float4*)&t[rr][k];
      acc[rr] += w0*tv.x + w1*tv.y + w2*tv.z + w3*tv.w;
    }
  }
  const int head = tid >> 6, lane = tid & 63;
  const float as = a_src[head*64 + lane];
  const float ad = a_dst[head*64 + lane];
  #pragma unroll
  for (int rr = 0; rr < 32; ++rr) {
    int rown = block0 + rr;
    if (rown >= N) break;
    float hv = acc[rr];
    h1h[(size_t)rown*256 + j] = (_Float16)hv;
    float ps = hv * as, pd = hv * ad;
    #pragma unroll
    for (int o = 32; o; o >>= 1) { ps += __shfl_xor(ps, o); pd += __shfl_xor(pd, o); }
    if (lane == 0) { es[rown*4 + head] = ps; ed[rown*4 + head] = pd; }
  }
}

// ------------- layer1 aggregation (CSR, wave per dst, unroll-4) + fused exp/log map ------
__global__ void k_agg1_csr(const int* __restrict__ rowptr, const int* __restrict__ csrc,
                           const float* __restrict__ es, const float* __restrict__ ed,
                           const _Float16* __restrict__ h1h, float* __restrict__ t2, int N) {
  int tidg = blockIdx.x*blockDim.x + threadIdx.x;
  int wid = tidg >> 6, lane = tidg & 63;
  int nw = (gridDim.x * blockDim.x) >> 6;
  const int h = lane >> 4;
  for (int d = wid; d < N; d += nw) {
    const int beg = rowptr[d], end = rowptr[d+1];
    const float edv = ed[d*4 + h];
    float4 acc = make_float4(0.f,0.f,0.f,0.f);
    float wsum = 0.f;
    int k = beg;
    for (; k + 4 <= end; k += 4) {
      int s0 = csrc[k], s1 = csrc[k+1], s2 = csrc[k+2], s3 = csrc[k+3];
      float w0 = __expf(lrelu02(es[s0*4 + h] + edv));
      float w1 = __expf(lrelu02(es[s1*4 + h] + edv));
      float w2 = __expf(lrelu02(es[s2*4 + h] + edv));
      float w3 = __expf(lrelu02(es[s3*4 + h] + edv));
      half4 v0 = *(const half4*)(h1h + (size_t)s0*256 + lane*4);
      half4 v1 = *(const half4*)(h1h + (size_t)s1*256 + lane*4);
      half4 v2 = *(const half4*)(h1h + (size_t)s2*256 + lane*4);
      half4 v3 = *(const half4*)(h1h + (size_t)s3*256 + lane*4);
      wsum += (w0 + w1) + (w2 + w3);
      acc.x += w0*(float)v0.x + w1*(float)v1.x + w2*(float)v2.x + w3*(float)v3.x;
      acc.y += w0*(float)v0.y + w1*(float)v1.y + w2*(float)v2.y + w3*(float)v3.y;
      acc.z += w0*(float)v0.z + w1*(float)v1.z + w2*(float)v2.z + w3*(float)v3.z;
      acc.w += w0*(float)v0.w + w1*(float)v1.w + w2*(float)v2.w + w3*(float)v3.w;
    }
    for (; k < end; ++k) {
      int s = csrc[k];
      float w = __expf(lrelu02(es[s*4 + h] + edv));
      wsum += w;
      half4 hv = *(const half4*)(h1h + (size_t)s*256 + lane*4);
      acc.x += w*(float)hv.x; acc.y += w*(float)hv.y;
      acc.z += w*(float)hv.z; acc.w += w*(float)hv.w;
    }
    float inv = 1.f / (wsum + 1e-16f);
    float ax = acc.x*inv, ay = acc.y*inv, az = acc.z*inv, aw = acc.w*inv;
    float ss = ax*ax + ay*ay + az*az + aw*aw;
    #pragma unroll
    for (int o = 32; o; o >>= 1) ss += __shfl_xor(ss, o);
    float n  = fmaxf(sqrtf(ss), EPSF);
    float s1 = tanhf(n) / n;                    // expmap0 scale
    float n2 = fmaxf(s1 * n, EPSF);             // = tanh(n), clamped
    float nc = fminf(n2, 1.f - 1e-5f);
    float sc = s1 * atanhf(nc) / n2;
    *(float4*)(t2 + (size_t)d*256 + lane*4) =
        make_float4(ax*sc, ay*sc, az*sc, aw*sc);
  }
}

// ------------- layer2: t2 [N,256] @ W2 [256,64] -> h2 (fp16) [N,64]; es2/ed2 [N] ---------
__global__ __launch_bounds__(256) void k_gemm2(
    const float* __restrict__ t2, const float* __restrict__ W2,
    const float* __restrict__ a_src, const float* __restrict__ a_dst,
    _Float16* __restrict__ h2h, float* __restrict__ es, float* __restrict__ ed, int N) {
  __shared__ float tile[32*256];                // 32 KB
  const int tid = threadIdx.x;
  const int block0 = blockIdx.x * 32;
  int validf4 = (block0 < N ? ((N - block0 < 32) ? (N - block0) : 32) : 0) * 64;
  const float4* srcp = (const float4*)(t2 + (size_t)block0 * 256);
  for (int i = tid; i < 2048; i += 256) {
    float4 v = (i < validf4) ? srcp[i] : make_float4(0,0,0,0);
    ((float4*)tile)[i] = v;
  }
  __syncthreads();
  const int j = tid & 63, g = tid >> 6;
  float acc[8];
  #pragma unroll
  for (int rr = 0; rr < 8; ++rr) acc[rr] = 0.f;
  const float* trow = &tile[(g*8)*256];
  for (int k = 0; k < 256; k += 4) {
    float w0 = W2[(size_t)(k+0)*64 + j];
    float w1 = W2[(size_t)(k+1)*64 + j];
    float w2v = W2[(size_t)(k+2)*64 + j];
    float w3 = W2[(size_t)(k+3)*64 + j];
    #pragma unroll
    for (int rr = 0; rr < 8; ++rr) {
      float4 tv = *(const float4*)&trow[rr*256 + k];
      acc[rr] += w0*tv.x + w1*tv.y + w2v*tv.z + w3*tv.w;
    }
  }
  const float as = a_src[j], ad = a_dst[j];
  #pragma unroll
  for (int rr = 0; rr < 8; ++rr) {
    int row = block0 + g*8 + rr;
    if (row < N) {
      float hv = acc[rr];
      h2h[(size_t)row*64 + j] = (_Float16)hv;
      float ps = hv*as, pd = hv*ad;
      #pragma unroll
      for (int o = 32; o; o >>= 1) { ps += __shfl_xor(ps,o); pd += __shfl_xor(pd,o); }
      if (j == 0) { es[row] = ps; ed[row] = pd; }
    }
  }
}

// ------------- layer2 aggregation (CSR, wave per dst, unroll-4) + fused expmap0 ----------
__global__ void k_agg2_csr(const int* __restrict__ rowptr, const int* __restrict__ csrc,
                           const float* __restrict__ es, const float* __restrict__ ed,
                           const _Float16* __restrict__ h2h, float* __restrict__ out, int N) {
  int tidg = blockIdx.x*blockDim.x + threadIdx.x;
  int wid = tidg >> 6, lane = tidg & 63;
  int nw = (gridDim.x * blockDim.x) >> 6;
  for (int d = wid; d < N; d += nw) {
    const int beg = rowptr[d], end = rowptr[d+1];
    const float edv = ed[d];
    float acc = 0.f, wsum = 0.f;
    int k = beg;
    for (; k + 4 <= end; k += 4) {
      int s0 = csrc[k], s1 = csrc[k+1], s2 = csrc[k+2], s3 = csrc[k+3];
      float w0 = __expf(lrelu02(es[s0] + edv));
      float w1 = __expf(lrelu02(es[s1] + edv));
      float w2 = __expf(lrelu02(es[s2] + edv));
      float w3 = __expf(lrelu02(es[s3] + edv));
      float x0 = (float)h2h[(size_t)s0*64 + lane];
      float x1 = (float)h2h[(size_t)s1*64 + lane];
      float x2 = (float)h2h[(size_t)s2*64 + lane];
      float x3 = (float)h2h[(size_t)s3*64 + lane];
      wsum += (w0 + w1) + (w2 + w3);
      acc += w0*x0 + w1*x1 + w2*x2 + w3*x3;
    }
    for (; k < end; ++k) {
      int s = csrc[k];
      float w = __expf(lrelu02(es[s] + edv));
      wsum += w;
      acc += w * (float)h2h[(size_t)s*64 + lane];
    }
    float a = acc / (wsum + 1e-16f);
    float ss = a*a;
    #pragma unroll
    for (int o = 32; o; o >>= 1) ss += __shfl_xor(ss, o);
    float n  = fmaxf(sqrtf(ss), EPSF);
    float sc = tanhf(n) / n;                    // expmap0 scale
    out[(size_t)d*64 + lane] = a * sc;
  }
}

extern "C" void kernel_launch(void* const* d_in, const int* in_sizes, int n_in,
                              void* d_out, int out_size, void* d_ws, size_t ws_size,
                              hipStream_t stream) {
  const float* x      = (const float*)d_in[0];
  const float* W1     = (const float*)d_in[1];
  const float* a_src1 = (const float*)d_in[2];
  const float* a_dst1 = (const float*)d_in[3];
  const float* W2     = (const float*)d_in[4];
  const float* a_src2 = (const float*)d_in[5];
  const float* a_dst2 = (const float*)d_in[6];
  const int*   ei0    = (const int*)d_in[7];
  const int*   ei1    = (const int*)d_in[8];
  const int N  = in_sizes[0] / 128;
  const int E0 = in_sizes[7] / 2;
  const int E1 = in_sizes[8] / 2;
  const int* src0 = ei0;  const int* dst0 = ei0 + E0;
  const int* src1 = ei1;  const int* dst1 = ei1 + E1;
  float* out = (float*)d_out;
  const int nb = (N + 127) >> 7;

  float* ws = (float*)d_ws;
  size_t o = 0;
  float* t2    = ws + o; o += (size_t)N*256;
  float* es1   = ws + o; o += (size_t)N*4;
  float* ed1   = ws + o; o += (size_t)N*4;
  float* es2   = ws + o; o += (size_t)N;
  float* ed2   = ws + o; o += (size_t)N;
  _Float16* h1h = (_Float16*)(ws + o); o += (size_t)N*128;  // N*256 halves
  _Float16* h2h = (_Float16*)(ws + o); o += (size_t)N*32;   // N*64 halves
  o += (o & 1);                                             // 8B align
  u64* temp0 = (u64*)(ws + o); o += (size_t)E0*2;
  u64* temp1 = (u64*)(ws + o); o += (size_t)E1*2;
  int* iws = (int*)(ws + o);
  size_t io = 0;
  int* cnt0    = iws + io; io += N;
  int* rowptr0 = iws + io; io += N + 1;
  int* cnt1    = iws + io; io += N + 1;
  int* rowptr1 = iws + io; io += N + 1;
  int* bcur0   = iws + io; io += NBMAX;
  int* bcur1   = iws + io; io += NBMAX;
  int* csrc0   = iws + io; io += E0;
  int* csrc1   = iws + io; io += E1;

  dim3 blk(256);
  // CSR build for both graphs (bucketed counting sort, no random 4B scatters)
  k_zero   <<<256, blk, 0, stream>>>(cnt0, cnt1, N);
  k_hist   <<<1024, blk, 0, stream>>>(dst0, cnt0, E0, dst1, cnt1, E1);
  k_scan2  <<<2, 1024, 0, stream>>>(cnt0, rowptr0, bcur0, cnt1, rowptr1, bcur1, N);
  k_bucketA<<<(E0+4095)/4096, blk, 0, stream>>>(src0, dst0, bcur0, temp0, E0, nb);
  k_bucketA<<<(E1+4095)/4096, blk, 0, stream>>>(src1, dst1, bcur1, temp1, E1, nb);
  k_bucketB<<<nb, blk, 0, stream>>>(temp0, rowptr0, csrc0, N);
  k_bucketB<<<nb, blk, 0, stream>>>(temp1, rowptr1, csrc1, N);
  // layer 1
  k_gemm1   <<<(N+31)/32, blk, 0, stream>>>(x, W1, a_src1, a_dst1, h1h, es1, ed1, N);
  k_agg1_csr<<<2048, blk, 0, stream>>>(rowptr0, csrc0, es1, ed1, h1h, t2, N);
  // layer 2
  k_gemm2   <<<(N+31)/32, blk, 0, stream>>>(t2, W2, a_src2, a_dst2, h2h, es2, ed2, N);
  k_agg2_csr<<<2048, blk, 0, stream>>>(rowptr1, csrc1, es2, ed2, h2h, out, N);
}

// Round 7
// 440.542 us; speedup vs baseline: 8.9524x; 1.0810x over previous
//
#include <hip/hip_runtime.h>

#define EPSF 1e-7f
#define NBMAX 512   // max dst-buckets (ceil(N/128)); N=50000 -> 391

typedef __attribute__((ext_vector_type(4))) _Float16 half4;
typedef unsigned long long u64;

__device__ __forceinline__ float lrelu02(float x){ return x > 0.f ? x : 0.2f*x; }

// ---------------- CSR build ----------------
__global__ void k_zero(int* __restrict__ cnt0, int* __restrict__ cnt1, int N) {
  int stride = gridDim.x * blockDim.x;
  for (int i = blockIdx.x*blockDim.x + threadIdx.x; i < N; i += stride) {
    cnt0[i] = 0; cnt1[i] = 0;
  }
}

__global__ void k_hist(const int* __restrict__ dst0, int* __restrict__ cnt0, int E0,
                       const int* __restrict__ dst1, int* __restrict__ cnt1, int E1) {
  int stride = gridDim.x * blockDim.x;
  int tid = blockIdx.x*blockDim.x + threadIdx.x;
  for (int i = tid; i < E0; i += stride) atomicAdd(&cnt0[dst0[i]], 1);
  for (int i = tid; i < E1; i += stride) atomicAdd(&cnt1[dst1[i]], 1);
}

// 2 blocks, 1024 threads: exclusive scan of cnt -> rowptr[0..n]; bucket cursors
__global__ __launch_bounds__(1024) void k_scan2(
    int* __restrict__ cnt0, int* __restrict__ rowptr0, int* __restrict__ bcur0,
    int* __restrict__ cnt1, int* __restrict__ rowptr1, int* __restrict__ bcur1, int n) {
  const int* cnt   = blockIdx.x ? cnt1    : cnt0;
  int* rowptr      = blockIdx.x ? rowptr1 : rowptr0;
  int* bcur        = blockIdx.x ? bcur1   : bcur0;
  __shared__ int wtot[16];
  const int tid = threadIdx.x;
  const int per = (n + 1023) / 1024;
  const int b = tid * per;
  const int e = min(b + per, n);
  int s = 0;
  for (int i = b; i < e; ++i) s += cnt[i];
  const int lane = tid & 63, w = tid >> 6;
  int v = s;
  #pragma unroll
  for (int o = 1; o < 64; o <<= 1) { int t = __shfl_up(v, o); if (lane >= o) v += t; }
  if (lane == 63) wtot[w] = v;
  __syncthreads();
  if (w == 0 && lane < 16) {
    int t = wtot[lane];
    #pragma unroll
    for (int o = 1; o < 16; o <<= 1) { int u = __shfl_up(t, o); if (lane >= o) t += u; }
    wtot[lane] = t;
  }
  __syncthreads();
  int base = (w > 0 ? wtot[w-1] : 0) + (v - s);
  for (int i = b; i < e; ++i) {
    rowptr[i] = base;
    if ((i & 127) == 0) bcur[i >> 7] = base;   // bucket cursor start
    base += cnt[i];
  }
  if (b < n && e == n) rowptr[n] = base;
}

// pass A: bucket edges by dst>>7 into temp (packed (dst<<32)|src), runs block-clustered
__global__ __launch_bounds__(256) void k_bucketA(
    const int* __restrict__ src, const int* __restrict__ dst,
    int* __restrict__ bcur, u64* __restrict__ temp, int E, int nb) {
  __shared__ int hist[NBMAX];
  __shared__ int lbase[NBMAX];
  const int tid = threadIdx.x;
  const int chunk0 = blockIdx.x * 4096;
  const int e_end = min(chunk0 + 4096, E);
  for (int i = tid; i < nb; i += 256) hist[i] = 0;
  __syncthreads();
  for (int i = chunk0 + tid; i < e_end; i += 256)
    atomicAdd(&hist[dst[i] >> 7], 1);
  __syncthreads();
  for (int bn = tid; bn < nb; bn += 256) {
    int c = hist[bn];
    lbase[bn] = c ? atomicAdd(&bcur[bn], c) : 0;
    hist[bn] = 0;
  }
  __syncthreads();
  for (int i = chunk0 + tid; i < e_end; i += 256) {
    int d = dst[i];
    int bn = d >> 7;
    int off = atomicAdd(&hist[bn], 1);
    temp[(size_t)lbase[bn] + off] = ((u64)(unsigned)d << 32) | (unsigned)src[i];
  }
}

// pass B: within-bucket ordering -> csrc (one block per bucket; writes L2-local)
__global__ __launch_bounds__(256) void k_bucketB(
    const u64* __restrict__ temp, const int* __restrict__ rowptr,
    int* __restrict__ csrc, int N) {
  __shared__ int lcur[128];
  const int tid = threadIdx.x;
  const int d0 = blockIdx.x << 7;
  const int d1 = min(d0 + 128, N);
  for (int i = tid; i < d1 - d0; i += 256) lcur[i] = rowptr[d0 + i];
  __syncthreads();
  const int lo = rowptr[d0], hi = rowptr[d1];
  for (int k = lo + tid; k < hi; k += 256) {
    u64 p = temp[k];
    int d = (int)(p >> 32);
    int s = (int)(unsigned)p;
    int pos = atomicAdd(&lcur[d - d0], 1);
    csrc[pos] = s;
  }
}

// ------------- layer1: logmap0(x) @ W1 -> h1 (fp16) [N,256]; es1/ed1 [N,4]
//   j-blocked: lane owns cols j=lane*4..lane*4+3; wave owns 16 rows; block = 64 rows
__global__ __launch_bounds__(256) void k_gemm1(
    const float* __restrict__ x, const float* __restrict__ W1,
    const float* __restrict__ a_src, const float* __restrict__ a_dst,
    _Float16* __restrict__ h1h, float* __restrict__ es, float* __restrict__ ed, int N) {
  __shared__ float t[64][128];          // 32 KB
  const int tid = threadIdx.x;
  const int block0 = blockIdx.x * 64;
  // preamble: 8 passes of 8 rows; 32 lanes/row, float4 each; logmap0 per row
  #pragma unroll
  for (int p = 0; p < 8; ++p) {
    const int r = (tid >> 5) + p*8, c = (tid & 31) * 4;
    const int row = block0 + r;
    float4 v = make_float4(0.f,0.f,0.f,0.f);
    if (row < N) v = *(const float4*)(x + (size_t)row*128 + c);
    float ss = v.x*v.x + v.y*v.y + v.z*v.z + v.w*v.w;
    #pragma unroll
    for (int o = 16; o; o >>= 1) ss += __shfl_xor(ss, o);
    float n  = fmaxf(sqrtf(ss), EPSF);
    float nc = fminf(n, 1.f - 1e-5f);
    float sc = atanhf(nc) / n;                 // logmap0 scale
    *(float4*)&t[r][c] = make_float4(v.x*sc, v.y*sc, v.z*sc, v.w*sc);
  }
  __syncthreads();

  const int wv = tid >> 6, lane = tid & 63;
  const int j = lane * 4;               // columns j..j+3
  const int r0 = wv * 16;               // wave's 16 rows
  float4 acc[16];
  #pragma unroll
  for (int r = 0; r < 16; ++r) acc[r] = make_float4(0.f,0.f,0.f,0.f);
  for (int k = 0; k < 128; k += 4) {
    float4 w0 = *(const float4*)(W1 + (size_t)(k+0)*256 + j);
    float4 w1 = *(const float4*)(W1 + (size_t)(k+1)*256 + j);
    float4 w2 = *(const float4*)(W1 + (size_t)(k+2)*256 + j);
    float4 w3 = *(const float4*)(W1 + (size_t)(k+3)*256 + j);
    #pragma unroll
    for (int r = 0; r < 16; ++r) {
      float4 tv = *(const float4*)&t[r0 + r][k];   // wave-uniform addr: broadcast
      acc[r].x += tv.x*w0.x + tv.y*w1.x + tv.z*w2.x + tv.w*w3.x;
      acc[r].y += tv.x*w0.y + tv.y*w1.y + tv.z*w2.y + tv.w*w3.y;
      acc[r].z += tv.x*w0.z + tv.y*w1.z + tv.z*w2.z + tv.w*w3.z;
      acc[r].w += tv.x*w0.w + tv.y*w1.w + tv.z*w2.w + tv.w*w3.w;
    }
  }
  const int head = lane >> 4;
  const float4 as4 = *(const float4*)(a_src + j);   // j = head*64 + (lane&15)*4
  const float4 ad4 = *(const float4*)(a_dst + j);
  #pragma unroll
  for (int r = 0; r < 16; ++r) {
    int row = block0 + r0 + r;
    if (row >= N) break;
    float4 a = acc[r];
    half4 hv; hv.x = (_Float16)a.x; hv.y = (_Float16)a.y;
              hv.z = (_Float16)a.z; hv.w = (_Float16)a.w;
    *(half4*)(h1h + (size_t)row*256 + j) = hv;
    float ps = a.x*as4.x + a.y*as4.y + a.z*as4.z + a.w*as4.w;
    float pd = a.x*ad4.x + a.y*ad4.y + a.z*ad4.z + a.w*ad4.w;
    #pragma unroll
    for (int o = 8; o; o >>= 1) { ps += __shfl_xor(ps, o); pd += __shfl_xor(pd, o); }
    if ((lane & 15) == 0) { es[row*4 + head] = ps; ed[row*4 + head] = pd; }
  }
}

// ------------- layer1 aggregation (CSR, wave per dst, unroll-4) + fused exp/log map ------
__global__ void k_agg1_csr(const int* __restrict__ rowptr, const int* __restrict__ csrc,
                           const float* __restrict__ es, const float* __restrict__ ed,
                           const _Float16* __restrict__ h1h, float* __restrict__ t2, int N) {
  int tidg = blockIdx.x*blockDim.x + threadIdx.x;
  int wid = tidg >> 6, lane = tidg & 63;
  int nw = (gridDim.x * blockDim.x) >> 6;
  const int h = lane >> 4;
  for (int d = wid; d < N; d += nw) {
    const int beg = rowptr[d], end = rowptr[d+1];
    const float edv = ed[d*4 + h];
    float4 acc = make_float4(0.f,0.f,0.f,0.f);
    float wsum = 0.f;
    int k = beg;
    for (; k + 4 <= end; k += 4) {
      int s0 = csrc[k], s1 = csrc[k+1], s2 = csrc[k+2], s3 = csrc[k+3];
      float w0 = __expf(lrelu02(es[s0*4 + h] + edv));
      float w1 = __expf(lrelu02(es[s1*4 + h] + edv));
      float w2 = __expf(lrelu02(es[s2*4 + h] + edv));
      float w3 = __expf(lrelu02(es[s3*4 + h] + edv));
      half4 v0 = *(const half4*)(h1h + (size_t)s0*256 + lane*4);
      half4 v1 = *(const half4*)(h1h + (size_t)s1*256 + lane*4);
      half4 v2 = *(const half4*)(h1h + (size_t)s2*256 + lane*4);
      half4 v3 = *(const half4*)(h1h + (size_t)s3*256 + lane*4);
      wsum += (w0 + w1) + (w2 + w3);
      acc.x += w0*(float)v0.x + w1*(float)v1.x + w2*(float)v2.x + w3*(float)v3.x;
      acc.y += w0*(float)v0.y + w1*(float)v1.y + w2*(float)v2.y + w3*(float)v3.y;
      acc.z += w0*(float)v0.z + w1*(float)v1.z + w2*(float)v2.z + w3*(float)v3.z;
      acc.w += w0*(float)v0.w + w1*(float)v1.w + w2*(float)v2.w + w3*(float)v3.w;
    }
    for (; k < end; ++k) {
      int s = csrc[k];
      float w = __expf(lrelu02(es[s*4 + h] + edv));
      wsum += w;
      half4 hv = *(const half4*)(h1h + (size_t)s*256 + lane*4);
      acc.x += w*(float)hv.x; acc.y += w*(float)hv.y;
      acc.z += w*(float)hv.z; acc.w += w*(float)hv.w;
    }
    float inv = 1.f / (wsum + 1e-16f);
    float ax = acc.x*inv, ay = acc.y*inv, az = acc.z*inv, aw = acc.w*inv;
    float ss = ax*ax + ay*ay + az*az + aw*aw;
    #pragma unroll
    for (int o = 32; o; o >>= 1) ss += __shfl_xor(ss, o);
    float n  = fmaxf(sqrtf(ss), EPSF);
    float s1 = tanhf(n) / n;                    // expmap0 scale
    float n2 = fmaxf(s1 * n, EPSF);             // = tanh(n), clamped
    float nc = fminf(n2, 1.f - 1e-5f);
    float sc = s1 * atanhf(nc) / n2;
    *(float4*)(t2 + (size_t)d*256 + lane*4) =
        make_float4(ax*sc, ay*sc, az*sc, aw*sc);
  }
}

// ------------- layer2: t2 [N,256] @ W2 [256,64] -> h2 (fp16) [N,64]; es2/ed2 [N]
//   j-blocked: lane owns cols jj=(lane&15)*4; rowgroup rg=lane>>4; block = 64 rows
__global__ __launch_bounds__(256) void k_gemm2(
    const float* __restrict__ t2, const float* __restrict__ W2,
    const float* __restrict__ a_src, const float* __restrict__ a_dst,
    _Float16* __restrict__ h2h, float* __restrict__ es, float* __restrict__ ed, int N) {
  __shared__ float tile[64*256];                // 64 KB
  const int tid = threadIdx.x;
  const int block0 = blockIdx.x * 64;
  int validf4 = (block0 < N ? ((N - block0 < 64) ? (N - block0) : 64) : 0) * 64;
  const float4* srcp = (const float4*)(t2 + (size_t)block0 * 256);
  float4* dstp = (float4*)tile;
  #pragma unroll
  for (int i0 = 0; i0 < 4096; i0 += 256) {
    int i = i0 + tid;
    dstp[i] = (i < validf4) ? srcp[i] : make_float4(0.f,0.f,0.f,0.f);
  }
  __syncthreads();
  const int wv = tid >> 6, lane = tid & 63;
  const int jj = (lane & 15) * 4;               // columns jj..jj+3
  const int rg = lane >> 4;                     // rowgroup 0..3
  const int rbase = wv*16 + rg*4;               // wave's rows: rbase..rbase+3
  float4 acc[4];
  #pragma unroll
  for (int rr = 0; rr < 4; ++rr) acc[rr] = make_float4(0.f,0.f,0.f,0.f);
  for (int k = 0; k < 256; k += 4) {
    float4 w0 = *(const float4*)(W2 + (size_t)(k+0)*64 + jj);
    float4 w1 = *(const float4*)(W2 + (size_t)(k+1)*64 + jj);
    float4 w2 = *(const float4*)(W2 + (size_t)(k+2)*64 + jj);
    float4 w3 = *(const float4*)(W2 + (size_t)(k+3)*64 + jj);
    #pragma unroll
    for (int rr = 0; rr < 4; ++rr) {
      float4 tv = *(const float4*)&tile[(rbase + rr)*256 + k]; // 16-lane broadcast
      acc[rr].x += tv.x*w0.x + tv.y*w1.x + tv.z*w2.x + tv.w*w3.x;
      acc[rr].y += tv.x*w0.y + tv.y*w1.y + tv.z*w2.y + tv.w*w3.y;
      acc[rr].z += tv.x*w0.z + tv.y*w1.z + tv.z*w2.z + tv.w*w3.z;
      acc[rr].w += tv.x*w0.w + tv.y*w1.w + tv.z*w2.w + tv.w*w3.w;
    }
  }
  const float4 as4 = *(const float4*)(a_src + jj);
  const float4 ad4 = *(const float4*)(a_dst + jj);
  #pragma unroll
  for (int rr = 0; rr < 4; ++rr) {
    int row = block0 + rbase + rr;
    if (row < N) {
      float4 a = acc[rr];
      half4 hv; hv.x = (_Float16)a.x; hv.y = (_Float16)a.y;
                hv.z = (_Float16)a.z; hv.w = (_Float16)a.w;
      *(half4*)(h2h + (size_t)row*64 + jj) = hv;
      float ps = a.x*as4.x + a.y*as4.y + a.z*as4.z + a.w*as4.w;
      float pd = a.x*ad4.x + a.y*ad4.y + a.z*ad4.z + a.w*ad4.w;
      #pragma unroll
      for (int o = 8; o; o >>= 1) { ps += __shfl_xor(ps, o); pd += __shfl_xor(pd, o); }
      if ((lane & 15) == 0) { es[row] = ps; ed[row] = pd; }
    }
  }
}

// ------------- layer2 aggregation (CSR, wave per dst, unroll-4) + fused expmap0 ----------
__global__ void k_agg2_csr(const int* __restrict__ rowptr, const int* __restrict__ csrc,
                           const float* __restrict__ es, const float* __restrict__ ed,
                           const _Float16* __restrict__ h2h, float* __restrict__ out, int N) {
  int tidg = blockIdx.x*blockDim.x + threadIdx.x;
  int wid = tidg >> 6, lane = tidg & 63;
  int nw = (gridDim.x * blockDim.x) >> 6;
  for (int d = wid; d < N; d += nw) {
    const int beg = rowptr[d], end = rowptr[d+1];
    const float edv = ed[d];
    float acc = 0.f, wsum = 0.f;
    int k = beg;
    for (; k + 4 <= end; k += 4) {
      int s0 = csrc[k], s1 = csrc[k+1], s2 = csrc[k+2], s3 = csrc[k+3];
      float w0 = __expf(lrelu02(es[s0] + edv));
      float w1 = __expf(lrelu02(es[s1] + edv));
      float w2 = __expf(lrelu02(es[s2] + edv));
      float w3 = __expf(lrelu02(es[s3] + edv));
      float x0 = (float)h2h[(size_t)s0*64 + lane];
      float x1 = (float)h2h[(size_t)s1*64 + lane];
      float x2 = (float)h2h[(size_t)s2*64 + lane];
      float x3 = (float)h2h[(size_t)s3*64 + lane];
      wsum += (w0 + w1) + (w2 + w3);
      acc += w0*x0 + w1*x1 + w2*x2 + w3*x3;
    }
    for (; k < end; ++k) {
      int s = csrc[k];
      float w = __expf(lrelu02(es[s] + edv));
      wsum += w;
      acc += w * (float)h2h[(size_t)s*64 + lane];
    }
    float a = acc / (wsum + 1e-16f);
    float ss = a*a;
    #pragma unroll
    for (int o = 32; o; o >>= 1) ss += __shfl_xor(ss, o);
    float n  = fmaxf(sqrtf(ss), EPSF);
    float sc = tanhf(n) / n;                    // expmap0 scale
    out[(size_t)d*64 + lane] = a * sc;
  }
}

extern "C" void kernel_launch(void* const* d_in, const int* in_sizes, int n_in,
                              void* d_out, int out_size, void* d_ws, size_t ws_size,
                              hipStream_t stream) {
  const float* x      = (const float*)d_in[0];
  const float* W1     = (const float*)d_in[1];
  const float* a_src1 = (const float*)d_in[2];
  const float* a_dst1 = (const float*)d_in[3];
  const float* W2     = (const float*)d_in[4];
  const float* a_src2 = (const float*)d_in[5];
  const float* a_dst2 = (const float*)d_in[6];
  const int*   ei0    = (const int*)d_in[7];
  const int*   ei1    = (const int*)d_in[8];
  const int N  = in_sizes[0] / 128;
  const int E0 = in_sizes[7] / 2;
  const int E1 = in_sizes[8] / 2;
  const int* src0 = ei0;  const int* dst0 = ei0 + E0;
  const int* src1 = ei1;  const int* dst1 = ei1 + E1;
  float* out = (float*)d_out;
  const int nb = (N + 127) >> 7;

  float* ws = (float*)d_ws;
  size_t o = 0;
  float* t2    = ws + o; o += (size_t)N*256;
  float* es1   = ws + o; o += (size_t)N*4;
  float* ed1   = ws + o; o += (size_t)N*4;
  float* es2   = ws + o; o += (size_t)N;
  float* ed2   = ws + o; o += (size_t)N;
  _Float16* h1h = (_Float16*)(ws + o); o += (size_t)N*128;  // N*256 halves
  _Float16* h2h = (_Float16*)(ws + o); o += (size_t)N*32;   // N*64 halves
  o += (o & 1);                                             // 8B align
  u64* temp0 = (u64*)(ws + o); o += (size_t)E0*2;
  u64* temp1 = (u64*)(ws + o); o += (size_t)E1*2;
  int* iws = (int*)(ws + o);
  size_t io = 0;
  int* cnt0    = iws + io; io += N;
  int* rowptr0 = iws + io; io += N + 1;
  int* cnt1    = iws + io; io += N + 1;
  int* rowptr1 = iws + io; io += N + 1;
  int* bcur0   = iws + io; io += NBMAX;
  int* bcur1   = iws + io; io += NBMAX;
  int* csrc0   = iws + io; io += E0;
  int* csrc1   = iws + io; io += E1;

  dim3 blk(256);
  // CSR build for both graphs (bucketed counting sort, no random 4B scatters)
  k_zero   <<<256, blk, 0, stream>>>(cnt0, cnt1, N);
  k_hist   <<<1024, blk, 0, stream>>>(dst0, cnt0, E0, dst1, cnt1, E1);
  k_scan2  <<<2, 1024, 0, stream>>>(cnt0, rowptr0, bcur0, cnt1, rowptr1, bcur1, N);
  k_bucketA<<<(E0+4095)/4096, blk, 0, stream>>>(src0, dst0, bcur0, temp0, E0, nb);
  k_bucketA<<<(E1+4095)/4096, blk, 0, stream>>>(src1, dst1, bcur1, temp1, E1, nb);
  k_bucketB<<<nb, blk, 0, stream>>>(temp0, rowptr0, csrc0, N);
  k_bucketB<<<nb, blk, 0, stream>>>(temp1, rowptr1, csrc1, N);
  // layer 1
  k_gemm1   <<<(N+63)/64, blk, 0, stream>>>(x, W1, a_src1, a_dst1, h1h, es1, ed1, N);
  k_agg1_csr<<<2048, blk, 0, stream>>>(rowptr0, csrc0, es1, ed1, h1h, t2, N);
  // layer 2
  k_gemm2   <<<(N+63)/64, blk, 0, stream>>>(t2, W2, a_src2, a_dst2, h2h, es2, ed2, N);
  k_agg2_csr<<<2048, blk, 0, stream>>>(rowptr1, csrc1, es2, ed2, h2h, out, N);
}

// Round 10
// 439.010 us; speedup vs baseline: 8.9836x; 1.0035x over previous
//
#include <hip/hip_runtime.h>

#define EPSF 1e-7f
#define NBMAX 512   // max dst-buckets (ceil(N/128)); N=50000 -> 391

typedef __attribute__((ext_vector_type(4))) _Float16 half4;
typedef unsigned long long u64;

__device__ __forceinline__ float lrelu02(float x){ return x > 0.f ? x : 0.2f*x; }

// ---------------- CSR build ----------------
__global__ void k_zero(int* __restrict__ cnt0, int* __restrict__ cnt1, int N) {
  int stride = gridDim.x * blockDim.x;
  for (int i = blockIdx.x*blockDim.x + threadIdx.x; i < N; i += stride) {
    cnt0[i] = 0; cnt1[i] = 0;
  }
}

__global__ void k_hist(const int* __restrict__ dst0, int* __restrict__ cnt0, int E0,
                       const int* __restrict__ dst1, int* __restrict__ cnt1, int E1) {
  int stride = gridDim.x * blockDim.x;
  int tid = blockIdx.x*blockDim.x + threadIdx.x;
  for (int i = tid; i < E0; i += stride) atomicAdd(&cnt0[dst0[i]], 1);
  for (int i = tid; i < E1; i += stride) atomicAdd(&cnt1[dst1[i]], 1);
}

// 2 blocks, 1024 threads: exclusive scan of cnt -> rowptr[0..n]; bucket cursors
__global__ __launch_bounds__(1024) void k_scan2(
    int* __restrict__ cnt0, int* __restrict__ rowptr0, int* __restrict__ bcur0,
    int* __restrict__ cnt1, int* __restrict__ rowptr1, int* __restrict__ bcur1, int n) {
  const int* cnt   = blockIdx.x ? cnt1    : cnt0;
  int* rowptr      = blockIdx.x ? rowptr1 : rowptr0;
  int* bcur        = blockIdx.x ? bcur1   : bcur0;
  __shared__ int wtot[16];
  const int tid = threadIdx.x;
  const int per = (n + 1023) / 1024;
  const int b = tid * per;
  const int e = min(b + per, n);
  int s = 0;
  for (int i = b; i < e; ++i) s += cnt[i];
  const int lane = tid & 63, w = tid >> 6;
  int v = s;
  #pragma unroll
  for (int o = 1; o < 64; o <<= 1) { int t = __shfl_up(v, o); if (lane >= o) v += t; }
  if (lane == 63) wtot[w] = v;
  __syncthreads();
  if (w == 0 && lane < 16) {
    int t = wtot[lane];
    #pragma unroll
    for (int o = 1; o < 16; o <<= 1) { int u = __shfl_up(t, o); if (lane >= o) t += u; }
    wtot[lane] = t;
  }
  __syncthreads();
  int base = (w > 0 ? wtot[w-1] : 0) + (v - s);
  for (int i = b; i < e; ++i) {
    rowptr[i] = base;
    if ((i & 127) == 0) bcur[i >> 7] = base;   // bucket cursor start
    base += cnt[i];
  }
  if (b < n && e == n) rowptr[n] = base;
}

// pass A: bucket edges by dst>>7 into temp (packed (dst<<32)|src), runs block-clustered
__global__ __launch_bounds__(256) void k_bucketA(
    const int* __restrict__ src, const int* __restrict__ dst,
    int* __restrict__ bcur, u64* __restrict__ temp, int E, int nb) {
  __shared__ int hist[NBMAX];
  __shared__ int lbase[NBMAX];
  const int tid = threadIdx.x;
  const int chunk0 = blockIdx.x * 4096;
  const int e_end = min(chunk0 + 4096, E);
  for (int i = tid; i < nb; i += 256) hist[i] = 0;
  __syncthreads();
  for (int i = chunk0 + tid; i < e_end; i += 256)
    atomicAdd(&hist[dst[i] >> 7], 1);
  __syncthreads();
  for (int bn = tid; bn < nb; bn += 256) {
    int c = hist[bn];
    lbase[bn] = c ? atomicAdd(&bcur[bn], c) : 0;
    hist[bn] = 0;
  }
  __syncthreads();
  for (int i = chunk0 + tid; i < e_end; i += 256) {
    int d = dst[i];
    int bn = d >> 7;
    int off = atomicAdd(&hist[bn], 1);
    temp[(size_t)lbase[bn] + off] = ((u64)(unsigned)d << 32) | (unsigned)src[i];
  }
}

// pass B: within-bucket ordering -> csrc (one block per bucket; writes L2-local)
__global__ __launch_bounds__(256) void k_bucketB(
    const u64* __restrict__ temp, const int* __restrict__ rowptr,
    int* __restrict__ csrc, int N) {
  __shared__ int lcur[128];
  const int tid = threadIdx.x;
  const int d0 = blockIdx.x << 7;
  const int d1 = min(d0 + 128, N);
  for (int i = tid; i < d1 - d0; i += 256) lcur[i] = rowptr[d0 + i];
  __syncthreads();
  const int lo = rowptr[d0], hi = rowptr[d1];
  for (int k = lo + tid; k < hi; k += 256) {
    u64 p = temp[k];
    int d = (int)(p >> 32);
    int s = (int)(unsigned)p;
    int pos = atomicAdd(&lcur[d - d0], 1);
    csrc[pos] = s;
  }
}

// ------------- layer1: logmap0(x) @ W1 -> h1 (fp16) [N,256]; es1/ed1 [N,4]
//   j-blocked: lane owns cols j=lane*4..lane*4+3; wave owns 8 rows; block = 32 rows
__global__ __launch_bounds__(256) void k_gemm1(
    const float* __restrict__ x, const float* __restrict__ W1,
    const float* __restrict__ a_src, const float* __restrict__ a_dst,
    _Float16* __restrict__ h1h, float* __restrict__ es, float* __restrict__ ed, int N) {
  __shared__ float t[32][128];          // 16 KB
  const int tid = threadIdx.x;
  const int block0 = blockIdx.x * 32;
  // preamble: 4 passes of 8 rows; 32 lanes/row, float4 each; logmap0 per row
  #pragma unroll
  for (int p = 0; p < 4; ++p) {
    const int r = (tid >> 5) + p*8, c = (tid & 31) * 4;
    const int row = block0 + r;
    float4 v = make_float4(0.f,0.f,0.f,0.f);
    if (row < N) v = *(const float4*)(x + (size_t)row*128 + c);
    float ss = v.x*v.x + v.y*v.y + v.z*v.z + v.w*v.w;
    #pragma unroll
    for (int o = 16; o; o >>= 1) ss += __shfl_xor(ss, o);
    float n  = fmaxf(sqrtf(ss), EPSF);
    float nc = fminf(n, 1.f - 1e-5f);
    float sc = atanhf(nc) / n;                 // logmap0 scale
    *(float4*)&t[r][c] = make_float4(v.x*sc, v.y*sc, v.z*sc, v.w*sc);
  }
  __syncthreads();

  const int wv = tid >> 6, lane = tid & 63;
  const int j = lane * 4;               // columns j..j+3
  const int r0 = wv * 8;                // wave's 8 rows
  float4 acc[8];
  #pragma unroll
  for (int r = 0; r < 8; ++r) acc[r] = make_float4(0.f,0.f,0.f,0.f);
  for (int k = 0; k < 128; k += 4) {
    float4 w0 = *(const float4*)(W1 + (size_t)(k+0)*256 + j);
    float4 w1 = *(const float4*)(W1 + (size_t)(k+1)*256 + j);
    float4 w2 = *(const float4*)(W1 + (size_t)(k+2)*256 + j);
    float4 w3 = *(const float4*)(W1 + (size_t)(k+3)*256 + j);
    #pragma unroll
    for (int r = 0; r < 8; ++r) {
      float4 tv = *(const float4*)&t[r0 + r][k];   // wave-uniform addr: broadcast
      acc[r].x += tv.x*w0.x + tv.y*w1.x + tv.z*w2.x + tv.w*w3.x;
      acc[r].y += tv.x*w0.y + tv.y*w1.y + tv.z*w2.y + tv.w*w3.y;
      acc[r].z += tv.x*w0.z + tv.y*w1.z + tv.z*w2.z + tv.w*w3.z;
      acc[r].w += tv.x*w0.w + tv.y*w1.w + tv.z*w2.w + tv.w*w3.w;
    }
  }
  const int head = lane >> 4;
  const float4 as4 = *(const float4*)(a_src + j);   // j = head*64 + (lane&15)*4
  const float4 ad4 = *(const float4*)(a_dst + j);
  #pragma unroll
  for (int r = 0; r < 8; ++r) {
    int row = block0 + r0 + r;
    if (row >= N) break;
    float4 a = acc[r];
    half4 hv; hv.x = (_Float16)a.x; hv.y = (_Float16)a.y;
              hv.z = (_Float16)a.z; hv.w = (_Float16)a.w;
    *(half4*)(h1h + (size_t)row*256 + j) = hv;
    float ps = a.x*as4.x + a.y*as4.y + a.z*as4.z + a.w*as4.w;
    float pd = a.x*ad4.x + a.y*ad4.y + a.z*ad4.z + a.w*ad4.w;
    #pragma unroll
    for (int o = 8; o; o >>= 1) { ps += __shfl_xor(ps, o); pd += __shfl_xor(pd, o); }
    if ((lane & 15) == 0) { es[row*4 + head] = ps; ed[row*4 + head] = pd; }
  }
}

// ------------- layer1 aggregation (CSR, wave per dst, unroll-4) + fused exp/log map ------
__global__ void k_agg1_csr(const int* __restrict__ rowptr, const int* __restrict__ csrc,
                           const float* __restrict__ es, const float* __restrict__ ed,
                           const _Float16* __restrict__ h1h, float* __restrict__ t2, int N) {
  int tidg = blockIdx.x*blockDim.x + threadIdx.x;
  int wid = tidg >> 6, lane = tidg & 63;
  int nw = (gridDim.x * blockDim.x) >> 6;
  const int h = lane >> 4;
  for (int d = wid; d < N; d += nw) {
    const int beg = rowptr[d], end = rowptr[d+1];
    const float edv = ed[d*4 + h];
    float4 acc = make_float4(0.f,0.f,0.f,0.f);
    float wsum = 0.f;
    int k = beg;
    for (; k + 4 <= end; k += 4) {
      int s0 = csrc[k], s1 = csrc[k+1], s2 = csrc[k+2], s3 = csrc[k+3];
      float w0 = __expf(lrelu02(es[s0*4 + h] + edv));
      float w1 = __expf(lrelu02(es[s1*4 + h] + edv));
      float w2 = __expf(lrelu02(es[s2*4 + h] + edv));
      float w3 = __expf(lrelu02(es[s3*4 + h] + edv));
      half4 v0 = *(const half4*)(h1h + (size_t)s0*256 + lane*4);
      half4 v1 = *(const half4*)(h1h + (size_t)s1*256 + lane*4);
      half4 v2 = *(const half4*)(h1h + (size_t)s2*256 + lane*4);
      half4 v3 = *(const half4*)(h1h + (size_t)s3*256 + lane*4);
      wsum += (w0 + w1) + (w2 + w3);
      acc.x += w0*(float)v0.x + w1*(float)v1.x + w2*(float)v2.x + w3*(float)v3.x;
      acc.y += w0*(float)v0.y + w1*(float)v1.y + w2*(float)v2.y + w3*(float)v3.y;
      acc.z += w0*(float)v0.z + w1*(float)v1.z + w2*(float)v2.z + w3*(float)v3.z;
      acc.w += w0*(float)v0.w + w1*(float)v1.w + w2*(float)v2.w + w3*(float)v3.w;
    }
    for (; k < end; ++k) {
      int s = csrc[k];
      float w = __expf(lrelu02(es[s*4 + h] + edv));
      wsum += w;
      half4 hv = *(const half4*)(h1h + (size_t)s*256 + lane*4);
      acc.x += w*(float)hv.x; acc.y += w*(float)hv.y;
      acc.z += w*(float)hv.z; acc.w += w*(float)hv.w;
    }
    float inv = 1.f / (wsum + 1e-16f);
    float ax = acc.x*inv, ay = acc.y*inv, az = acc.z*inv, aw = acc.w*inv;
    float ss = ax*ax + ay*ay + az*az + aw*aw;
    #pragma unroll
    for (int o = 32; o; o >>= 1) ss += __shfl_xor(ss, o);
    float n  = fmaxf(sqrtf(ss), EPSF);
    float s1 = tanhf(n) / n;                    // expmap0 scale
    float n2 = fmaxf(s1 * n, EPSF);             // = tanh(n), clamped
    float nc = fminf(n2, 1.f - 1e-5f);
    float sc = s1 * atanhf(nc) / n2;
    *(float4*)(t2 + (size_t)d*256 + lane*4) =
        make_float4(ax*sc, ay*sc, az*sc, aw*sc);
  }
}

// ------------- layer2: t2 [N,256] @ W2 [256,64] -> h2 (fp16) [N,64]; es2/ed2 [N]
//   block = 32 rows; wave owns 8 rows (rg-pairs); lane owns cols jj=(lane&15)*4
#define T2PAD 260
__global__ __launch_bounds__(256) void k_gemm2(
    const float* __restrict__ t2, const float* __restrict__ W2,
    const float* __restrict__ a_src, const float* __restrict__ a_dst,
    _Float16* __restrict__ h2h, float* __restrict__ es, float* __restrict__ ed, int N) {
  __shared__ float tile[32*T2PAD];              // ~33 KB, padded rows (bank spread)
  const int tid = threadIdx.x;
  const int block0 = blockIdx.x * 32;
  int validf4 = (block0 < N ? ((N - block0 < 32) ? (N - block0) : 32) : 0) * 64;
  const float4* srcp = (const float4*)(t2 + (size_t)block0 * 256);
  #pragma unroll
  for (int i0 = 0; i0 < 2048; i0 += 256) {
    int i = i0 + tid;
    float4 v = (i < validf4) ? srcp[i] : make_float4(0.f,0.f,0.f,0.f);
    int r = i >> 6, c = (i & 63) * 4;
    *(float4*)&tile[r*T2PAD + c] = v;
  }
  __syncthreads();
  const int wv = tid >> 6, lane = tid & 63;
  const int jj = (lane & 15) * 4;               // columns jj..jj+3
  const int rg = lane >> 4;                     // rowgroup 0..3
  const int rbase = wv*8 + rg*2;                // wave's rows: rbase, rbase+1
  float4 acc[2];
  acc[0] = make_float4(0.f,0.f,0.f,0.f);
  acc[1] = make_float4(0.f,0.f,0.f,0.f);
  for (int k = 0; k < 256; k += 4) {
    float4 w0 = *(const float4*)(W2 + (size_t)(k+0)*64 + jj);
    float4 w1 = *(const float4*)(W2 + (size_t)(k+1)*64 + jj);
    float4 w2 = *(const float4*)(W2 + (size_t)(k+2)*64 + jj);
    float4 w3 = *(const float4*)(W2 + (size_t)(k+3)*64 + jj);
    #pragma unroll
    for (int rr = 0; rr < 2; ++rr) {
      float4 tv = *(const float4*)&tile[(rbase + rr)*T2PAD + k]; // 16-lane broadcast
      acc[rr].x += tv.x*w0.x + tv.y*w1.x + tv.z*w2.x + tv.w*w3.x;
      acc[rr].y += tv.x*w0.y + tv.y*w1.y + tv.z*w2.y + tv.w*w3.y;
      acc[rr].z += tv.x*w0.z + tv.y*w1.z + tv.z*w2.z + tv.w*w3.z;
      acc[rr].w += tv.x*w0.w + tv.y*w1.w + tv.z*w2.w + tv.w*w3.w;
    }
  }
  const float4 as4 = *(const float4*)(a_src + jj);
  const float4 ad4 = *(const float4*)(a_dst + jj);
  #pragma unroll
  for (int rr = 0; rr < 2; ++rr) {
    int row = block0 + rbase + rr;
    if (row < N) {
      float4 a = acc[rr];
      half4 hv; hv.x = (_Float16)a.x; hv.y = (_Float16)a.y;
                hv.z = (_Float16)a.z; hv.w = (_Float16)a.w;
      *(half4*)(h2h + (size_t)row*64 + jj) = hv;
      float ps = a.x*as4.x + a.y*as4.y + a.z*as4.z + a.w*as4.w;
      float pd = a.x*ad4.x + a.y*ad4.y + a.z*ad4.z + a.w*ad4.w;
      #pragma unroll
      for (int o = 8; o; o >>= 1) { ps += __shfl_xor(ps, o); pd += __shfl_xor(pd, o); }
      if ((lane & 15) == 0) { es[row] = ps; ed[row] = pd; }
    }
  }
}

// ------------- layer2 aggregation (CSR, wave per dst, unroll-4) + fused expmap0 ----------
__global__ void k_agg2_csr(const int* __restrict__ rowptr, const int* __restrict__ csrc,
                           const float* __restrict__ es, const float* __restrict__ ed,
                           const _Float16* __restrict__ h2h, float* __restrict__ out, int N) {
  int tidg = blockIdx.x*blockDim.x + threadIdx.x;
  int wid = tidg >> 6, lane = tidg & 63;
  int nw = (gridDim.x * blockDim.x) >> 6;
  for (int d = wid; d < N; d += nw) {
    const int beg = rowptr[d], end = rowptr[d+1];
    const float edv = ed[d];
    float acc = 0.f, wsum = 0.f;
    int k = beg;
    for (; k + 4 <= end; k += 4) {
      int s0 = csrc[k], s1 = csrc[k+1], s2 = csrc[k+2], s3 = csrc[k+3];
      float w0 = __expf(lrelu02(es[s0] + edv));
      float w1 = __expf(lrelu02(es[s1] + edv));
      float w2 = __expf(lrelu02(es[s2] + edv));
      float w3 = __expf(lrelu02(es[s3] + edv));
      float x0 = (float)h2h[(size_t)s0*64 + lane];
      float x1 = (float)h2h[(size_t)s1*64 + lane];
      float x2 = (float)h2h[(size_t)s2*64 + lane];
      float x3 = (float)h2h[(size_t)s3*64 + lane];
      wsum += (w0 + w1) + (w2 + w3);
      acc += w0*x0 + w1*x1 + w2*x2 + w3*x3;
    }
    for (; k < end; ++k) {
      int s = csrc[k];
      float w = __expf(lrelu02(es[s] + edv));
      wsum += w;
      acc += w * (float)h2h[(size_t)s*64 + lane];
    }
    float a = acc / (wsum + 1e-16f);
    float ss = a*a;
    #pragma unroll
    for (int o = 32; o; o >>= 1) ss += __shfl_xor(ss, o);
    float n  = fmaxf(sqrtf(ss), EPSF);
    float sc = tanhf(n) / n;                    // expmap0 scale
    out[(size_t)d*64 + lane] = a * sc;
  }
}

extern "C" void kernel_launch(void* const* d_in, const int* in_sizes, int n_in,
                              void* d_out, int out_size, void* d_ws, size_t ws_size,
                              hipStream_t stream) {
  const float* x      = (const float*)d_in[0];
  const float* W1     = (const float*)d_in[1];
  const float* a_src1 = (const float*)d_in[2];
  const float* a_dst1 = (const float*)d_in[3];
  const float* W2     = (const float*)d_in[4];
  const float* a_src2 = (const float*)d_in[5];
  const float* a_dst2 = (const float*)d_in[6];
  const int*   ei0    = (const int*)d_in[7];
  const int*   ei1    = (const int*)d_in[8];
  const int N  = in_sizes[0] / 128;
  const int E0 = in_sizes[7] / 2;
  const int E1 = in_sizes[8] / 2;
  const int* src0 = ei0;  const int* dst0 = ei0 + E0;
  const int* src1 = ei1;  const int* dst1 = ei1 + E1;
  float* out = (float*)d_out;
  const int nb = (N + 127) >> 7;

  float* ws = (float*)d_ws;
  size_t o = 0;
  float* t2    = ws + o; o += (size_t)N*256;
  float* es1   = ws + o; o += (size_t)N*4;
  float* ed1   = ws + o; o += (size_t)N*4;
  float* es2   = ws + o; o += (size_t)N;
  float* ed2   = ws + o; o += (size_t)N;
  _Float16* h1h = (_Float16*)(ws + o); o += (size_t)N*128;  // N*256 halves
  _Float16* h2h = (_Float16*)(ws + o); o += (size_t)N*32;   // N*64 halves
  o += (o & 1);                                             // 8B align
  u64* temp0 = (u64*)(ws + o); o += (size_t)E0*2;
  u64* temp1 = (u64*)(ws + o); o += (size_t)E1*2;
  int* iws = (int*)(ws + o);
  size_t io = 0;
  int* cnt0    = iws + io; io += N;
  int* rowptr0 = iws + io; io += N + 1;
  int* cnt1    = iws + io; io += N + 1;
  int* rowptr1 = iws + io; io += N + 1;
  int* bcur0   = iws + io; io += NBMAX;
  int* bcur1   = iws + io; io += NBMAX;
  int* csrc0   = iws + io; io += E0;
  int* csrc1   = iws + io; io += E1;

  dim3 blk(256);
  // CSR build for both graphs (bucketed counting sort, no random 4B scatters)
  k_zero   <<<256, blk, 0, stream>>>(cnt0, cnt1, N);
  k_hist   <<<1024, blk, 0, stream>>>(dst0, cnt0, E0, dst1, cnt1, E1);
  k_scan2  <<<2, 1024, 0, stream>>>(cnt0, rowptr0, bcur0, cnt1, rowptr1, bcur1, N);
  k_bucketA<<<(E0+4095)/4096, blk, 0, stream>>>(src0, dst0, bcur0, temp0, E0, nb);
  k_bucketA<<<(E1+4095)/4096, blk, 0, stream>>>(src1, dst1, bcur1, temp1, E1, nb);
  k_bucketB<<<nb, blk, 0, stream>>>(temp0, rowptr0, csrc0, N);
  k_bucketB<<<nb, blk, 0, stream>>>(temp1, rowptr1, csrc1, N);
  // layer 1
  k_gemm1   <<<(N+31)/32, blk, 0, stream>>>(x, W1, a_src1, a_dst1, h1h, es1, ed1, N);
  k_agg1_csr<<<2048, blk, 0, stream>>>(rowptr0, csrc0, es1, ed1, h1h, t2, N);
  // layer 2
  k_gemm2   <<<(N+31)/32, blk, 0, stream>>>(t2, W2, a_src2, a_dst2, h2h, es2, ed2, N);
  k_agg2_csr<<<2048, blk, 0, stream>>>(rowptr1, csrc1, es2, ed2, h2h, out, N);
}

// Round 11
// 331.112 us; speedup vs baseline: 11.9111x; 1.3259x over previous
//
#include <hip/hip_runtime.h>

#define EPSF 1e-7f
#define NBMAX 512   // max dst-buckets (ceil(N/128)); N=50000 -> 391

typedef __attribute__((ext_vector_type(4))) _Float16 half4;
typedef unsigned long long u64;

__device__ __forceinline__ float lrelu02(float x){ return x > 0.f ? x : 0.2f*x; }

// ---------------- CSR build (bucket-local, no N-sized scan) ----------------
// 1) per-block LDS histogram of dst>>7 -> global bucket counts
__global__ __launch_bounds__(256) void k_bhist(
    const int* __restrict__ dst0, int E0, const int* __restrict__ dst1, int E1,
    int* __restrict__ bcnt0, int* __restrict__ bcnt1, int nb) {
  __shared__ int h0[NBMAX], h1[NBMAX];
  const int tid = threadIdx.x;
  const int g = blockIdx.x*blockDim.x + tid;
  const int stride = gridDim.x*blockDim.x;
  for (int i = tid; i < nb; i += 256) { h0[i] = 0; h1[i] = 0; }
  __syncthreads();
  for (int i = g; i < E0; i += stride) atomicAdd(&h0[dst0[i] >> 7], 1);
  for (int i = g; i < E1; i += stride) atomicAdd(&h1[dst1[i] >> 7], 1);
  __syncthreads();
  for (int i = tid; i < nb; i += 256) {
    if (h0[i]) atomicAdd(&bcnt0[i], h0[i]);
    if (h1[i]) atomicAdd(&bcnt1[i], h1[i]);
  }
}

// 2) one block scans both graphs' bucket counts -> bucket bases + cursors
__global__ __launch_bounds__(1024) void k_bscan(
    const int* __restrict__ bcnt0, int* __restrict__ bbase0, int* __restrict__ bcur0,
    const int* __restrict__ bcnt1, int* __restrict__ bbase1, int* __restrict__ bcur1,
    int nb) {
  __shared__ int wt[16];
  const int tid = threadIdx.x;
  const int half = tid >> 9, idx = tid & 511;
  const int* bcnt = half ? bcnt1 : bcnt0;
  int* bbase = half ? bbase1 : bbase0;
  int* bcur  = half ? bcur1  : bcur0;
  int v = (idx < nb) ? bcnt[idx] : 0;
  const int lane = tid & 63, w = tid >> 6;
  int inc = v;
  #pragma unroll
  for (int o = 1; o < 64; o <<= 1) { int t = __shfl_up(inc, o); if (lane >= o) inc += t; }
  if (lane == 63) wt[w] = inc;
  __syncthreads();
  int woff = 0;
  for (int i = half*8; i < w; ++i) woff += wt[i];
  int excl = woff + inc - v;
  if (idx < nb) { bbase[idx] = excl; bcur[idx] = excl; }
  if (idx == nb-1) bbase[nb] = excl + v;
}

// 3) pass A: bucket edges by dst>>7 into temp (packed (dst<<32)|src), block-clustered
__global__ __launch_bounds__(256) void k_bucketA(
    const int* __restrict__ src, const int* __restrict__ dst,
    int* __restrict__ bcur, u64* __restrict__ temp, int E, int nb) {
  __shared__ int hist[NBMAX];
  __shared__ int lbase[NBMAX];
  const int tid = threadIdx.x;
  const int chunk0 = blockIdx.x * 4096;
  const int e_end = min(chunk0 + 4096, E);
  for (int i = tid; i < nb; i += 256) hist[i] = 0;
  __syncthreads();
  for (int i = chunk0 + tid; i < e_end; i += 256)
    atomicAdd(&hist[dst[i] >> 7], 1);
  __syncthreads();
  for (int bn = tid; bn < nb; bn += 256) {
    int c = hist[bn];
    lbase[bn] = c ? atomicAdd(&bcur[bn], c) : 0;
    hist[bn] = 0;
  }
  __syncthreads();
  for (int i = chunk0 + tid; i < e_end; i += 256) {
    int d = dst[i];
    int bn = d >> 7;
    int off = atomicAdd(&hist[bn], 1);
    temp[(size_t)lbase[bn] + off] = ((u64)(unsigned)d << 32) | (unsigned)src[i];
  }
}

// 4) pass B: per bucket, count per-dst + local scan -> rowptr; scatter csrc
__global__ __launch_bounds__(256) void k_bucketB2(
    const u64* __restrict__ temp, const int* __restrict__ bbase,
    int* __restrict__ rowptr, int* __restrict__ csrc, int N, int nb) {
  __shared__ int lcnt[128];
  __shared__ int lcur[128];
  __shared__ int wt4[4];
  const int tid = threadIdx.x;
  const int b = blockIdx.x;
  const int d0 = b << 7;
  const int d1 = min(d0 + 128, N);
  const int lo = bbase[b], hi = bbase[b+1];
  if (tid < 128) lcnt[tid] = 0;
  __syncthreads();
  for (int k = lo + tid; k < hi; k += 256)
    atomicAdd(&lcnt[(int)(temp[k] >> 32) - d0], 1);
  __syncthreads();
  // exclusive scan of lcnt[0..127] (threads 128..255 compute junk, unused)
  int v = (tid < 128) ? lcnt[tid] : 0;
  const int lane = tid & 63, w = tid >> 6;
  int inc = v;
  #pragma unroll
  for (int o = 1; o < 64; o <<= 1) { int t = __shfl_up(inc, o); if (lane >= o) inc += t; }
  if (lane == 63) wt4[w] = inc;
  __syncthreads();
  int woff = 0;
  for (int i = 0; i < w; ++i) woff += wt4[i];
  int excl = lo + woff + inc - v;
  if (tid < d1 - d0) { rowptr[d0 + tid] = excl; lcur[tid] = excl; }
  if (b == nb-1 && tid == 0) rowptr[N] = hi;
  __syncthreads();
  for (int k = lo + tid; k < hi; k += 256) {
    u64 p = temp[k];
    int d = (int)(p >> 32);
    int s = (int)(unsigned)p;
    int pos = atomicAdd(&lcur[d - d0], 1);
    csrc[pos] = s;
  }
}

// ------------- layer1: logmap0(x) @ W1 -> h1 (fp16) [N,256]; es1/ed1 [N,4]
//   j-blocked: lane owns cols j=lane*4..lane*4+3; wave owns 8 rows; block = 32 rows
__global__ __launch_bounds__(256) void k_gemm1(
    const float* __restrict__ x, const float* __restrict__ W1,
    const float* __restrict__ a_src, const float* __restrict__ a_dst,
    _Float16* __restrict__ h1h, float* __restrict__ es, float* __restrict__ ed, int N) {
  __shared__ float t[32][128];          // 16 KB
  const int tid = threadIdx.x;
  const int block0 = blockIdx.x * 32;
  // preamble: 4 passes of 8 rows; 32 lanes/row, float4 each; logmap0 per row
  #pragma unroll
  for (int p = 0; p < 4; ++p) {
    const int r = (tid >> 5) + p*8, c = (tid & 31) * 4;
    const int row = block0 + r;
    float4 v = make_float4(0.f,0.f,0.f,0.f);
    if (row < N) v = *(const float4*)(x + (size_t)row*128 + c);
    float ss = v.x*v.x + v.y*v.y + v.z*v.z + v.w*v.w;
    #pragma unroll
    for (int o = 16; o; o >>= 1) ss += __shfl_xor(ss, o);
    float n  = fmaxf(sqrtf(ss), EPSF);
    float nc = fminf(n, 1.f - 1e-5f);
    float sc = atanhf(nc) / n;                 // logmap0 scale
    *(float4*)&t[r][c] = make_float4(v.x*sc, v.y*sc, v.z*sc, v.w*sc);
  }
  __syncthreads();

  const int wv = tid >> 6, lane = tid & 63;
  const int j = lane * 4;               // columns j..j+3
  const int r0 = wv * 8;                // wave's 8 rows
  float4 acc[8];
  #pragma unroll
  for (int r = 0; r < 8; ++r) acc[r] = make_float4(0.f,0.f,0.f,0.f);
  for (int k = 0; k < 128; k += 4) {
    float4 w0 = *(const float4*)(W1 + (size_t)(k+0)*256 + j);
    float4 w1 = *(const float4*)(W1 + (size_t)(k+1)*256 + j);
    float4 w2 = *(const float4*)(W1 + (size_t)(k+2)*256 + j);
    float4 w3 = *(const float4*)(W1 + (size_t)(k+3)*256 + j);
    #pragma unroll
    for (int r = 0; r < 8; ++r) {
      float4 tv = *(const float4*)&t[r0 + r][k];   // wave-uniform addr: broadcast
      acc[r].x += tv.x*w0.x + tv.y*w1.x + tv.z*w2.x + tv.w*w3.x;
      acc[r].y += tv.x*w0.y + tv.y*w1.y + tv.z*w2.y + tv.w*w3.y;
      acc[r].z += tv.x*w0.z + tv.y*w1.z + tv.z*w2.z + tv.w*w3.z;
      acc[r].w += tv.x*w0.w + tv.y*w1.w + tv.z*w2.w + tv.w*w3.w;
    }
  }
  const int head = lane >> 4;
  const float4 as4 = *(const float4*)(a_src + j);   // j = head*64 + (lane&15)*4
  const float4 ad4 = *(const float4*)(a_dst + j);
  #pragma unroll
  for (int r = 0; r < 8; ++r) {
    int row = block0 + r0 + r;
    if (row >= N) break;
    float4 a = acc[r];
    half4 hv; hv.x = (_Float16)a.x; hv.y = (_Float16)a.y;
              hv.z = (_Float16)a.z; hv.w = (_Float16)a.w;
    *(half4*)(h1h + (size_t)row*256 + j) = hv;
    float ps = a.x*as4.x + a.y*as4.y + a.z*as4.z + a.w*as4.w;
    float pd = a.x*ad4.x + a.y*ad4.y + a.z*ad4.z + a.w*ad4.w;
    #pragma unroll
    for (int o = 8; o; o >>= 1) { ps += __shfl_xor(ps, o); pd += __shfl_xor(pd, o); }
    if ((lane & 15) == 0) { es[row*4 + head] = ps; ed[row*4 + head] = pd; }
  }
}

// ------------- layer1 aggregation (CSR, wave per dst, unroll-4) + fused exp/log map ------
__global__ void k_agg1_csr(const int* __restrict__ rowptr, const int* __restrict__ csrc,
                           const float* __restrict__ es, const float* __restrict__ ed,
                           const _Float16* __restrict__ h1h, float* __restrict__ t2, int N) {
  int tidg = blockIdx.x*blockDim.x + threadIdx.x;
  int wid = tidg >> 6, lane = tidg & 63;
  int nw = (gridDim.x * blockDim.x) >> 6;
  const int h = lane >> 4;
  for (int d = wid; d < N; d += nw) {
    const int beg = rowptr[d], end = rowptr[d+1];
    const float edv = ed[d*4 + h];
    float4 acc = make_float4(0.f,0.f,0.f,0.f);
    float wsum = 0.f;
    int k = beg;
    for (; k + 4 <= end; k += 4) {
      int s0 = csrc[k], s1 = csrc[k+1], s2 = csrc[k+2], s3 = csrc[k+3];
      float w0 = __expf(lrelu02(es[s0*4 + h] + edv));
      float w1 = __expf(lrelu02(es[s1*4 + h] + edv));
      float w2 = __expf(lrelu02(es[s2*4 + h] + edv));
      float w3 = __expf(lrelu02(es[s3*4 + h] + edv));
      half4 v0 = *(const half4*)(h1h + (size_t)s0*256 + lane*4);
      half4 v1 = *(const half4*)(h1h + (size_t)s1*256 + lane*4);
      half4 v2 = *(const half4*)(h1h + (size_t)s2*256 + lane*4);
      half4 v3 = *(const half4*)(h1h + (size_t)s3*256 + lane*4);
      wsum += (w0 + w1) + (w2 + w3);
      acc.x += w0*(float)v0.x + w1*(float)v1.x + w2*(float)v2.x + w3*(float)v3.x;
      acc.y += w0*(float)v0.y + w1*(float)v1.y + w2*(float)v2.y + w3*(float)v3.y;
      acc.z += w0*(float)v0.z + w1*(float)v1.z + w2*(float)v2.z + w3*(float)v3.z;
      acc.w += w0*(float)v0.w + w1*(float)v1.w + w2*(float)v2.w + w3*(float)v3.w;
    }
    for (; k < end; ++k) {
      int s = csrc[k];
      float w = __expf(lrelu02(es[s*4 + h] + edv));
      wsum += w;
      half4 hv = *(const half4*)(h1h + (size_t)s*256 + lane*4);
      acc.x += w*(float)hv.x; acc.y += w*(float)hv.y;
      acc.z += w*(float)hv.z; acc.w += w*(float)hv.w;
    }
    float inv = 1.f / (wsum + 1e-16f);
    float ax = acc.x*inv, ay = acc.y*inv, az = acc.z*inv, aw = acc.w*inv;
    float ss = ax*ax + ay*ay + az*az + aw*aw;
    #pragma unroll
    for (int o = 32; o; o >>= 1) ss += __shfl_xor(ss, o);
    float n  = fmaxf(sqrtf(ss), EPSF);
    float s1 = tanhf(n) / n;                    // expmap0 scale
    float n2 = fmaxf(s1 * n, EPSF);             // = tanh(n), clamped
    float nc = fminf(n2, 1.f - 1e-5f);
    float sc = s1 * atanhf(nc) / n2;
    *(float4*)(t2 + (size_t)d*256 + lane*4) =
        make_float4(ax*sc, ay*sc, az*sc, aw*sc);
  }
}

// ------------- layer2: t2 [N,256] @ W2 [256,64] -> h2 (fp16) [N,64]; es2/ed2 [N]
//   block = 32 rows; wave owns 8 rows (rg-pairs); lane owns cols jj=(lane&15)*4
#define T2PAD 260
__global__ __launch_bounds__(256) void k_gemm2(
    const float* __restrict__ t2, const float* __restrict__ W2,
    const float* __restrict__ a_src, const float* __restrict__ a_dst,
    _Float16* __restrict__ h2h, float* __restrict__ es, float* __restrict__ ed, int N) {
  __shared__ float tile[32*T2PAD];              // ~33 KB, padded rows (bank spread)
  const int tid = threadIdx.x;
  const int block0 = blockIdx.x * 32;
  int validf4 = (block0 < N ? ((N - block0 < 32) ? (N - block0) : 32) : 0) * 64;
  const float4* srcp = (const float4*)(t2 + (size_t)block0 * 256);
  #pragma unroll
  for (int i0 = 0; i0 < 2048; i0 += 256) {
    int i = i0 + tid;
    float4 v = (i < validf4) ? srcp[i] : make_float4(0.f,0.f,0.f,0.f);
    int r = i >> 6, c = (i & 63) * 4;
    *(float4*)&tile[r*T2PAD + c] = v;
  }
  __syncthreads();
  const int wv = tid >> 6, lane = tid & 63;
  const int jj = (lane & 15) * 4;               // columns jj..jj+3
  const int rg = lane >> 4;                     // rowgroup 0..3
  const int rbase = wv*8 + rg*2;                // wave's rows: rbase, rbase+1
  float4 acc[2];
  acc[0] = make_float4(0.f,0.f,0.f,0.f);
  acc[1] = make_float4(0.f,0.f,0.f,0.f);
  for (int k = 0; k < 256; k += 4) {
    float4 w0 = *(const float4*)(W2 + (size_t)(k+0)*64 + jj);
    float4 w1 = *(const float4*)(W2 + (size_t)(k+1)*64 + jj);
    float4 w2 = *(const float4*)(W2 + (size_t)(k+2)*64 + jj);
    float4 w3 = *(const float4*)(W2 + (size_t)(k+3)*64 + jj);
    #pragma unroll
    for (int rr = 0; rr < 2; ++rr) {
      float4 tv = *(const float4*)&tile[(rbase + rr)*T2PAD + k]; // 16-lane broadcast
      acc[rr].x += tv.x*w0.x + tv.y*w1.x + tv.z*w2.x + tv.w*w3.x;
      acc[rr].y += tv.x*w0.y + tv.y*w1.y + tv.z*w2.y + tv.w*w3.y;
      acc[rr].z += tv.x*w0.z + tv.y*w1.z + tv.z*w2.z + tv.w*w3.z;
      acc[rr].w += tv.x*w0.w + tv.y*w1.w + tv.z*w2.w + tv.w*w3.w;
    }
  }
  const float4 as4 = *(const float4*)(a_src + jj);
  const float4 ad4 = *(const float4*)(a_dst + jj);
  #pragma unroll
  for (int rr = 0; rr < 2; ++rr) {
    int row = block0 + rbase + rr;
    if (row < N) {
      float4 a = acc[rr];
      half4 hv; hv.x = (_Float16)a.x; hv.y = (_Float16)a.y;
                hv.z = (_Float16)a.z; hv.w = (_Float16)a.w;
      *(half4*)(h2h + (size_t)row*64 + jj) = hv;
      float ps = a.x*as4.x + a.y*as4.y + a.z*as4.z + a.w*as4.w;
      float pd = a.x*ad4.x + a.y*ad4.y + a.z*ad4.z + a.w*ad4.w;
      #pragma unroll
      for (int o = 8; o; o >>= 1) { ps += __shfl_xor(ps, o); pd += __shfl_xor(pd, o); }
      if ((lane & 15) == 0) { es[row] = ps; ed[row] = pd; }
    }
  }
}

// ------------- layer2 aggregation (CSR, wave per dst, unroll-4) + fused expmap0 ----------
__global__ void k_agg2_csr(const int* __restrict__ rowptr, const int* __restrict__ csrc,
                           const float* __restrict__ es, const float* __restrict__ ed,
                           const _Float16* __restrict__ h2h, float* __restrict__ out, int N) {
  int tidg = blockIdx.x*blockDim.x + threadIdx.x;
  int wid = tidg >> 6, lane = tidg & 63;
  int nw = (gridDim.x * blockDim.x) >> 6;
  for (int d = wid; d < N; d += nw) {
    const int beg = rowptr[d], end = rowptr[d+1];
    const float edv = ed[d];
    float acc = 0.f, wsum = 0.f;
    int k = beg;
    for (; k + 4 <= end; k += 4) {
      int s0 = csrc[k], s1 = csrc[k+1], s2 = csrc[k+2], s3 = csrc[k+3];
      float w0 = __expf(lrelu02(es[s0] + edv));
      float w1 = __expf(lrelu02(es[s1] + edv));
      float w2 = __expf(lrelu02(es[s2] + edv));
      float w3 = __expf(lrelu02(es[s3] + edv));
      float x0 = (float)h2h[(size_t)s0*64 + lane];
      float x1 = (float)h2h[(size_t)s1*64 + lane];
      float x2 = (float)h2h[(size_t)s2*64 + lane];
      float x3 = (float)h2h[(size_t)s3*64 + lane];
      wsum += (w0 + w1) + (w2 + w3);
      acc += w0*x0 + w1*x1 + w2*x2 + w3*x3;
    }
    for (; k < end; ++k) {
      int s = csrc[k];
      float w = __expf(lrelu02(es[s] + edv));
      wsum += w;
      acc += w * (float)h2h[(size_t)s*64 + lane];
    }
    float a = acc / (wsum + 1e-16f);
    float ss = a*a;
    #pragma unroll
    for (int o = 32; o; o >>= 1) ss += __shfl_xor(ss, o);
    float n  = fmaxf(sqrtf(ss), EPSF);
    float sc = tanhf(n) / n;                    // expmap0 scale
    out[(size_t)d*64 + lane] = a * sc;
  }
}

extern "C" void kernel_launch(void* const* d_in, const int* in_sizes, int n_in,
                              void* d_out, int out_size, void* d_ws, size_t ws_size,
                              hipStream_t stream) {
  const float* x      = (const float*)d_in[0];
  const float* W1     = (const float*)d_in[1];
  const float* a_src1 = (const float*)d_in[2];
  const float* a_dst1 = (const float*)d_in[3];
  const float* W2     = (const float*)d_in[4];
  const float* a_src2 = (const float*)d_in[5];
  const float* a_dst2 = (const float*)d_in[6];
  const int*   ei0    = (const int*)d_in[7];
  const int*   ei1    = (const int*)d_in[8];
  const int N  = in_sizes[0] / 128;
  const int E0 = in_sizes[7] / 2;
  const int E1 = in_sizes[8] / 2;
  const int* src0 = ei0;  const int* dst0 = ei0 + E0;
  const int* src1 = ei1;  const int* dst1 = ei1 + E1;
  float* out = (float*)d_out;
  const int nb = (N + 127) >> 7;

  float* ws = (float*)d_ws;
  size_t o = 0;
  float* t2    = ws + o; o += (size_t)N*256;
  float* es1   = ws + o; o += (size_t)N*4;
  float* ed1   = ws + o; o += (size_t)N*4;
  float* es2   = ws + o; o += (size_t)N;
  float* ed2   = ws + o; o += (size_t)N;
  _Float16* h1h = (_Float16*)(ws + o); o += (size_t)N*128;  // N*256 halves
  _Float16* h2h = (_Float16*)(ws + o); o += (size_t)N*32;   // N*64 halves
  o += (o & 1);                                             // 8B align
  u64* temp0 = (u64*)(ws + o); o += (size_t)E0*2;
  u64* temp1 = (u64*)(ws + o); o += (size_t)E1*2;
  int* iws = (int*)(ws + o);
  size_t io = 0;
  int* rowptr0 = iws + io; io += N + 1;
  int* rowptr1 = iws + io; io += N + 1;
  int* bcnt0   = iws + io; io += NBMAX;  // bcnt0/bcnt1 adjacent: one memset
  int* bcnt1   = iws + io; io += NBMAX;
  int* bbase0  = iws + io; io += NBMAX + 1;
  int* bbase1  = iws + io; io += NBMAX + 1;
  int* bcur0   = iws + io; io += NBMAX;
  int* bcur1   = iws + io; io += NBMAX;
  int* csrc0   = iws + io; io += E0;
  int* csrc1   = iws + io; io += E1;

  dim3 blk(256);
  // CSR build: bucket counts -> tiny scan -> bucketed scatter -> bucket-local rowptr
  hipMemsetAsync(bcnt0, 0, 2*NBMAX*sizeof(int), stream);
  k_bhist  <<<1024, blk, 0, stream>>>(dst0, E0, dst1, E1, bcnt0, bcnt1, nb);
  k_bscan  <<<1, 1024, 0, stream>>>(bcnt0, bbase0, bcur0, bcnt1, bbase1, bcur1, nb);
  k_bucketA<<<(E0+4095)/4096, blk, 0, stream>>>(src0, dst0, bcur0, temp0, E0, nb);
  k_bucketA<<<(E1+4095)/4096, blk, 0, stream>>>(src1, dst1, bcur1, temp1, E1, nb);
  k_bucketB2<<<nb, blk, 0, stream>>>(temp0, bbase0, rowptr0, csrc0, N, nb);
  k_bucketB2<<<nb, blk, 0, stream>>>(temp1, bbase1, rowptr1, csrc1, N, nb);
  // layer 1
  k_gemm1   <<<(N+31)/32, blk, 0, stream>>>(x, W1, a_src1, a_dst1, h1h, es1, ed1, N);
  k_agg1_csr<<<2048, blk, 0, stream>>>(rowptr0, csrc0, es1, ed1, h1h, t2, N);
  // layer 2
  k_gemm2   <<<(N+31)/32, blk, 0, stream>>>(t2, W2, a_src2, a_dst2, h2h, es2, ed2, N);
  k_agg2_csr<<<2048, blk, 0, stream>>>(rowptr1, csrc1, es2, ed2, h2h, out, N);
}

// Round 12
// 322.694 us; speedup vs baseline: 12.2218x; 1.0261x over previous
//
#include <hip/hip_runtime.h>

#define EPSF 1e-7f
#define NBMAX 512   // max dst-buckets (ceil(N/128)); N=50000 -> 391

typedef __attribute__((ext_vector_type(4))) _Float16 half4;
typedef unsigned long long u64;

__device__ __forceinline__ float lrelu02(float x){ return x > 0.f ? x : 0.2f*x; }

// ---------------- CSR build (bucket-local, no N-sized scan) ----------------
// 1) per-block LDS histogram of dst>>7 -> global bucket counts
__global__ __launch_bounds__(256) void k_bhist(
    const int* __restrict__ dst0, int E0, const int* __restrict__ dst1, int E1,
    int* __restrict__ bcnt0, int* __restrict__ bcnt1, int nb) {
  __shared__ int h0[NBMAX], h1[NBMAX];
  const int tid = threadIdx.x;
  const int g = blockIdx.x*blockDim.x + tid;
  const int stride = gridDim.x*blockDim.x;
  for (int i = tid; i < nb; i += 256) { h0[i] = 0; h1[i] = 0; }
  __syncthreads();
  for (int i = g; i < E0; i += stride) atomicAdd(&h0[dst0[i] >> 7], 1);
  for (int i = g; i < E1; i += stride) atomicAdd(&h1[dst1[i] >> 7], 1);
  __syncthreads();
  for (int i = tid; i < nb; i += 256) {
    if (h0[i]) atomicAdd(&bcnt0[i], h0[i]);
    if (h1[i]) atomicAdd(&bcnt1[i], h1[i]);
  }
}

// 2) one block scans both graphs' bucket counts -> bucket bases + cursors
__global__ __launch_bounds__(1024) void k_bscan(
    const int* __restrict__ bcnt0, int* __restrict__ bbase0, int* __restrict__ bcur0,
    const int* __restrict__ bcnt1, int* __restrict__ bbase1, int* __restrict__ bcur1,
    int nb) {
  __shared__ int wt[16];
  const int tid = threadIdx.x;
  const int half = tid >> 9, idx = tid & 511;
  const int* bcnt = half ? bcnt1 : bcnt0;
  int* bbase = half ? bbase1 : bbase0;
  int* bcur  = half ? bcur1  : bcur0;
  int v = (idx < nb) ? bcnt[idx] : 0;
  const int lane = tid & 63, w = tid >> 6;
  int inc = v;
  #pragma unroll
  for (int o = 1; o < 64; o <<= 1) { int t = __shfl_up(inc, o); if (lane >= o) inc += t; }
  if (lane == 63) wt[w] = inc;
  __syncthreads();
  int woff = 0;
  for (int i = half*8; i < w; ++i) woff += wt[i];
  int excl = woff + inc - v;
  if (idx < nb) { bbase[idx] = excl; bcur[idx] = excl; }
  if (idx == nb-1) bbase[nb] = excl + v;
}

// 3) pass A (both graphs in one launch): bucket edges by dst>>7 into temp
__global__ __launch_bounds__(256) void k_bucketA(
    const int* __restrict__ src0, const int* __restrict__ dst0,
    int* __restrict__ bcur0, u64* __restrict__ temp0, int E0, int blocksA0,
    const int* __restrict__ src1, const int* __restrict__ dst1,
    int* __restrict__ bcur1, u64* __restrict__ temp1, int E1, int nb) {
  const int g0 = (blockIdx.x < blocksA0);
  const int* src = g0 ? src0 : src1;
  const int* dst = g0 ? dst0 : dst1;
  int* bcur      = g0 ? bcur0 : bcur1;
  u64* temp      = g0 ? temp0 : temp1;
  const int E    = g0 ? E0 : E1;
  const int cb   = g0 ? blockIdx.x : blockIdx.x - blocksA0;
  __shared__ int hist[NBMAX];
  __shared__ int lbase[NBMAX];
  const int tid = threadIdx.x;
  const int chunk0 = cb * 4096;
  const int e_end = min(chunk0 + 4096, E);
  for (int i = tid; i < nb; i += 256) hist[i] = 0;
  __syncthreads();
  for (int i = chunk0 + tid; i < e_end; i += 256)
    atomicAdd(&hist[dst[i] >> 7], 1);
  __syncthreads();
  for (int bn = tid; bn < nb; bn += 256) {
    int c = hist[bn];
    lbase[bn] = c ? atomicAdd(&bcur[bn], c) : 0;
    hist[bn] = 0;
  }
  __syncthreads();
  for (int i = chunk0 + tid; i < e_end; i += 256) {
    int d = dst[i];
    int bn = d >> 7;
    int off = atomicAdd(&hist[bn], 1);
    temp[(size_t)lbase[bn] + off] = ((u64)(unsigned)d << 32) | (unsigned)src[i];
  }
}

// 4) pass B (both graphs): per bucket, per-dst count + local scan -> rowptr; scatter csrc
__global__ __launch_bounds__(256) void k_bucketB2(
    const u64* __restrict__ temp0, const int* __restrict__ bbase0,
    int* __restrict__ rowptr0, int* __restrict__ csrc0,
    const u64* __restrict__ temp1, const int* __restrict__ bbase1,
    int* __restrict__ rowptr1, int* __restrict__ csrc1, int N, int nb) {
  const int g0 = (blockIdx.x < nb);
  const u64* temp = g0 ? temp0 : temp1;
  const int* bbase = g0 ? bbase0 : bbase1;
  int* rowptr = g0 ? rowptr0 : rowptr1;
  int* csrc   = g0 ? csrc0 : csrc1;
  const int b = g0 ? blockIdx.x : blockIdx.x - nb;
  __shared__ int lcnt[128];
  __shared__ int lcur[128];
  __shared__ int wt4[4];
  const int tid = threadIdx.x;
  const int d0 = b << 7;
  const int d1 = min(d0 + 128, N);
  const int lo = bbase[b], hi = bbase[b+1];
  if (tid < 128) lcnt[tid] = 0;
  __syncthreads();
  for (int k = lo + tid; k < hi; k += 256)
    atomicAdd(&lcnt[(int)(temp[k] >> 32) - d0], 1);
  __syncthreads();
  int v = (tid < 128) ? lcnt[tid] : 0;
  const int lane = tid & 63, w = tid >> 6;
  int inc = v;
  #pragma unroll
  for (int o = 1; o < 64; o <<= 1) { int t = __shfl_up(inc, o); if (lane >= o) inc += t; }
  if (lane == 63) wt4[w] = inc;
  __syncthreads();
  int woff = 0;
  for (int i = 0; i < w; ++i) woff += wt4[i];
  int excl = lo + woff + inc - v;
  if (tid < d1 - d0) { rowptr[d0 + tid] = excl; lcur[tid] = excl; }
  if (b == nb-1 && tid == 0) rowptr[N] = hi;
  __syncthreads();
  for (int k = lo + tid; k < hi; k += 256) {
    u64 p = temp[k];
    int d = (int)(p >> 32);
    int s = (int)(unsigned)p;
    int pos = atomicAdd(&lcur[d - d0], 1);
    csrc[pos] = s;
  }
}

// ------------- layer1: logmap0(x) @ W1 -> h1 (fp16) [N,256]; es1/ed1 [N,4]
//   j-blocked: lane owns cols j=lane*4..lane*4+3; wave owns 8 rows; block = 32 rows
__global__ __launch_bounds__(256) void k_gemm1(
    const float* __restrict__ x, const float* __restrict__ W1,
    const float* __restrict__ a_src, const float* __restrict__ a_dst,
    _Float16* __restrict__ h1h, float* __restrict__ es, float* __restrict__ ed, int N) {
  __shared__ float t[32][128];          // 16 KB
  const int tid = threadIdx.x;
  const int block0 = blockIdx.x * 32;
  #pragma unroll
  for (int p = 0; p < 4; ++p) {
    const int r = (tid >> 5) + p*8, c = (tid & 31) * 4;
    const int row = block0 + r;
    float4 v = make_float4(0.f,0.f,0.f,0.f);
    if (row < N) v = *(const float4*)(x + (size_t)row*128 + c);
    float ss = v.x*v.x + v.y*v.y + v.z*v.z + v.w*v.w;
    #pragma unroll
    for (int o = 16; o; o >>= 1) ss += __shfl_xor(ss, o);
    float n  = fmaxf(sqrtf(ss), EPSF);
    float nc = fminf(n, 1.f - 1e-5f);
    float sc = atanhf(nc) / n;                 // logmap0 scale
    *(float4*)&t[r][c] = make_float4(v.x*sc, v.y*sc, v.z*sc, v.w*sc);
  }
  __syncthreads();

  const int wv = tid >> 6, lane = tid & 63;
  const int j = lane * 4;               // columns j..j+3
  const int r0 = wv * 8;                // wave's 8 rows
  float4 acc[8];
  #pragma unroll
  for (int r = 0; r < 8; ++r) acc[r] = make_float4(0.f,0.f,0.f,0.f);
  for (int k = 0; k < 128; k += 4) {
    float4 w0 = *(const float4*)(W1 + (size_t)(k+0)*256 + j);
    float4 w1 = *(const float4*)(W1 + (size_t)(k+1)*256 + j);
    float4 w2 = *(const float4*)(W1 + (size_t)(k+2)*256 + j);
    float4 w3 = *(const float4*)(W1 + (size_t)(k+3)*256 + j);
    #pragma unroll
    for (int r = 0; r < 8; ++r) {
      float4 tv = *(const float4*)&t[r0 + r][k];   // wave-uniform addr: broadcast
      acc[r].x += tv.x*w0.x + tv.y*w1.x + tv.z*w2.x + tv.w*w3.x;
      acc[r].y += tv.x*w0.y + tv.y*w1.y + tv.z*w2.y + tv.w*w3.y;
      acc[r].z += tv.x*w0.z + tv.y*w1.z + tv.z*w2.z + tv.w*w3.z;
      acc[r].w += tv.x*w0.w + tv.y*w1.w + tv.z*w2.w + tv.w*w3.w;
    }
  }
  const int head = lane >> 4;
  const float4 as4 = *(const float4*)(a_src + j);
  const float4 ad4 = *(const float4*)(a_dst + j);
  #pragma unroll
  for (int r = 0; r < 8; ++r) {
    int row = block0 + r0 + r;
    if (row >= N) break;
    float4 a = acc[r];
    half4 hv; hv.x = (_Float16)a.x; hv.y = (_Float16)a.y;
              hv.z = (_Float16)a.z; hv.w = (_Float16)a.w;
    *(half4*)(h1h + (size_t)row*256 + j) = hv;
    float ps = a.x*as4.x + a.y*as4.y + a.z*as4.z + a.w*as4.w;
    float pd = a.x*ad4.x + a.y*ad4.y + a.z*ad4.z + a.w*ad4.w;
    #pragma unroll
    for (int o = 8; o; o >>= 1) { ps += __shfl_xor(ps, o); pd += __shfl_xor(pd, o); }
    if ((lane & 15) == 0) { es[row*4 + head] = ps; ed[row*4 + head] = pd; }
  }
}

// ------------- layer1 aggregation (CSR, wave per dst, unroll-8) + fused exp/log map
//               output t2 stored fp16 -------------
__global__ void k_agg1_csr(const int* __restrict__ rowptr, const int* __restrict__ csrc,
                           const float* __restrict__ es, const float* __restrict__ ed,
                           const _Float16* __restrict__ h1h, _Float16* __restrict__ t2h,
                           int N) {
  int tidg = blockIdx.x*blockDim.x + threadIdx.x;
  int wid = tidg >> 6, lane = tidg & 63;
  int nw = (gridDim.x * blockDim.x) >> 6;
  const int h = lane >> 4;
  for (int d = wid; d < N; d += nw) {
    const int beg = rowptr[d], end = rowptr[d+1];
    const float edv = ed[d*4 + h];
    float4 acc = make_float4(0.f,0.f,0.f,0.f);
    float wsum = 0.f;
    int k = beg;
    for (; k + 8 <= end; k += 8) {
      int s[8];
      #pragma unroll
      for (int i = 0; i < 8; ++i) s[i] = csrc[k+i];
      float wg[8];
      #pragma unroll
      for (int i = 0; i < 8; ++i) wg[i] = __expf(lrelu02(es[s[i]*4 + h] + edv));
      half4 v[8];
      #pragma unroll
      for (int i = 0; i < 8; ++i) v[i] = *(const half4*)(h1h + (size_t)s[i]*256 + lane*4);
      #pragma unroll
      for (int i = 0; i < 8; ++i) {
        wsum += wg[i];
        acc.x += wg[i]*(float)v[i].x; acc.y += wg[i]*(float)v[i].y;
        acc.z += wg[i]*(float)v[i].z; acc.w += wg[i]*(float)v[i].w;
      }
    }
    for (; k < end; ++k) {
      int s = csrc[k];
      float w = __expf(lrelu02(es[s*4 + h] + edv));
      wsum += w;
      half4 hv = *(const half4*)(h1h + (size_t)s*256 + lane*4);
      acc.x += w*(float)hv.x; acc.y += w*(float)hv.y;
      acc.z += w*(float)hv.z; acc.w += w*(float)hv.w;
    }
    float inv = 1.f / (wsum + 1e-16f);
    float ax = acc.x*inv, ay = acc.y*inv, az = acc.z*inv, aw = acc.w*inv;
    float ss = ax*ax + ay*ay + az*az + aw*aw;
    #pragma unroll
    for (int o = 32; o; o >>= 1) ss += __shfl_xor(ss, o);
    float n  = fmaxf(sqrtf(ss), EPSF);
    float s1 = tanhf(n) / n;                    // expmap0 scale
    float n2 = fmaxf(s1 * n, EPSF);             // = tanh(n), clamped
    float nc = fminf(n2, 1.f - 1e-5f);
    float sc = s1 * atanhf(nc) / n2;
    half4 o4; o4.x = (_Float16)(ax*sc); o4.y = (_Float16)(ay*sc);
              o4.z = (_Float16)(az*sc); o4.w = (_Float16)(aw*sc);
    *(half4*)(t2h + (size_t)d*256 + lane*4) = o4;
  }
}

// ------------- layer2: t2h (fp16) [N,256] @ W2 [256,64] -> h2 (fp16); es2/ed2 [N]
//   block = 32 rows; wave owns 8 rows (rg-pairs); lane owns cols jj=(lane&15)*4
#define T2PAD 260
__global__ __launch_bounds__(256) void k_gemm2(
    const _Float16* __restrict__ t2h, const float* __restrict__ W2,
    const float* __restrict__ a_src, const float* __restrict__ a_dst,
    _Float16* __restrict__ h2h, float* __restrict__ es, float* __restrict__ ed, int N) {
  __shared__ float tile[32*T2PAD];              // ~33 KB, padded rows (bank spread)
  const int tid = threadIdx.x;
  const int block0 = blockIdx.x * 32;
  int validq = (block0 < N ? ((N - block0 < 32) ? (N - block0) : 32) : 0) * 64;
  const half4* srcp = (const half4*)(t2h + (size_t)block0 * 256);
  #pragma unroll
  for (int i0 = 0; i0 < 2048; i0 += 256) {
    int i = i0 + tid;
    half4 v; v.x = v.y = v.z = v.w = (_Float16)0.f;
    if (i < validq) v = srcp[i];
    int r = i >> 6, c = (i & 63) * 4;
    *(float4*)&tile[r*T2PAD + c] =
        make_float4((float)v.x, (float)v.y, (float)v.z, (float)v.w);
  }
  __syncthreads();
  const int wv = tid >> 6, lane = tid & 63;
  const int jj = (lane & 15) * 4;               // columns jj..jj+3
  const int rg = lane >> 4;                     // rowgroup 0..3
  const int rbase = wv*8 + rg*2;                // wave's rows: rbase, rbase+1
  float4 acc[2];
  acc[0] = make_float4(0.f,0.f,0.f,0.f);
  acc[1] = make_float4(0.f,0.f,0.f,0.f);
  for (int k = 0; k < 256; k += 4) {
    float4 w0 = *(const float4*)(W2 + (size_t)(k+0)*64 + jj);
    float4 w1 = *(const float4*)(W2 + (size_t)(k+1)*64 + jj);
    float4 w2 = *(const float4*)(W2 + (size_t)(k+2)*64 + jj);
    float4 w3 = *(const float4*)(W2 + (size_t)(k+3)*64 + jj);
    #pragma unroll
    for (int rr = 0; rr < 2; ++rr) {
      float4 tv = *(const float4*)&tile[(rbase + rr)*T2PAD + k]; // 16-lane broadcast
      acc[rr].x += tv.x*w0.x + tv.y*w1.x + tv.z*w2.x + tv.w*w3.x;
      acc[rr].y += tv.x*w0.y + tv.y*w1.y + tv.z*w2.y + tv.w*w3.y;
      acc[rr].z += tv.x*w0.z + tv.y*w1.z + tv.z*w2.z + tv.w*w3.z;
      acc[rr].w += tv.x*w0.w + tv.y*w1.w + tv.z*w2.w + tv.w*w3.w;
    }
  }
  const float4 as4 = *(const float4*)(a_src + jj);
  const float4 ad4 = *(const float4*)(a_dst + jj);
  #pragma unroll
  for (int rr = 0; rr < 2; ++rr) {
    int row = block0 + rbase + rr;
    if (row < N) {
      float4 a = acc[rr];
      half4 hv; hv.x = (_Float16)a.x; hv.y = (_Float16)a.y;
                hv.z = (_Float16)a.z; hv.w = (_Float16)a.w;
      *(half4*)(h2h + (size_t)row*64 + jj) = hv;
      float ps = a.x*as4.x + a.y*as4.y + a.z*as4.z + a.w*as4.w;
      float pd = a.x*ad4.x + a.y*ad4.y + a.z*ad4.z + a.w*ad4.w;
      #pragma unroll
      for (int o = 8; o; o >>= 1) { ps += __shfl_xor(ps, o); pd += __shfl_xor(pd, o); }
      if ((lane & 15) == 0) { es[row] = ps; ed[row] = pd; }
    }
  }
}

// ------------- layer2 aggregation (CSR, wave per dst, unroll-4) + fused expmap0 ----------
__global__ void k_agg2_csr(const int* __restrict__ rowptr, const int* __restrict__ csrc,
                           const float* __restrict__ es, const float* __restrict__ ed,
                           const _Float16* __restrict__ h2h, float* __restrict__ out, int N) {
  int tidg = blockIdx.x*blockDim.x + threadIdx.x;
  int wid = tidg >> 6, lane = tidg & 63;
  int nw = (gridDim.x * blockDim.x) >> 6;
  for (int d = wid; d < N; d += nw) {
    const int beg = rowptr[d], end = rowptr[d+1];
    const float edv = ed[d];
    float acc = 0.f, wsum = 0.f;
    int k = beg;
    for (; k + 4 <= end; k += 4) {
      int s0 = csrc[k], s1 = csrc[k+1], s2 = csrc[k+2], s3 = csrc[k+3];
      float w0 = __expf(lrelu02(es[s0] + edv));
      float w1 = __expf(lrelu02(es[s1] + edv));
      float w2 = __expf(lrelu02(es[s2] + edv));
      float w3 = __expf(lrelu02(es[s3] + edv));
      float x0 = (float)h2h[(size_t)s0*64 + lane];
      float x1 = (float)h2h[(size_t)s1*64 + lane];
      float x2 = (float)h2h[(size_t)s2*64 + lane];
      float x3 = (float)h2h[(size_t)s3*64 + lane];
      wsum += (w0 + w1) + (w2 + w3);
      acc += w0*x0 + w1*x1 + w2*x2 + w3*x3;
    }
    for (; k < end; ++k) {
      int s = csrc[k];
      float w = __expf(lrelu02(es[s] + edv));
      wsum += w;
      acc += w * (float)h2h[(size_t)s*64 + lane];
    }
    float a = acc / (wsum + 1e-16f);
    float ss = a*a;
    #pragma unroll
    for (int o = 32; o; o >>= 1) ss += __shfl_xor(ss, o);
    float n  = fmaxf(sqrtf(ss), EPSF);
    float sc = tanhf(n) / n;                    // expmap0 scale
    out[(size_t)d*64 + lane] = a * sc;
  }
}

extern "C" void kernel_launch(void* const* d_in, const int* in_sizes, int n_in,
                              void* d_out, int out_size, void* d_ws, size_t ws_size,
                              hipStream_t stream) {
  const float* x      = (const float*)d_in[0];
  const float* W1     = (const float*)d_in[1];
  const float* a_src1 = (const float*)d_in[2];
  const float* a_dst1 = (const float*)d_in[3];
  const float* W2     = (const float*)d_in[4];
  const float* a_src2 = (const float*)d_in[5];
  const float* a_dst2 = (const float*)d_in[6];
  const int*   ei0    = (const int*)d_in[7];
  const int*   ei1    = (const int*)d_in[8];
  const int N  = in_sizes[0] / 128;
  const int E0 = in_sizes[7] / 2;
  const int E1 = in_sizes[8] / 2;
  const int* src0 = ei0;  const int* dst0 = ei0 + E0;
  const int* src1 = ei1;  const int* dst1 = ei1 + E1;
  float* out = (float*)d_out;
  const int nb = (N + 127) >> 7;

  float* ws = (float*)d_ws;
  size_t o = 0;
  float* es1   = ws + o; o += (size_t)N*4;
  float* ed1   = ws + o; o += (size_t)N*4;
  float* es2   = ws + o; o += (size_t)N;
  float* ed2   = ws + o; o += (size_t)N;
  _Float16* h1h = (_Float16*)(ws + o); o += (size_t)N*128;  // N*256 halves
  _Float16* t2h = (_Float16*)(ws + o); o += (size_t)N*128;  // N*256 halves
  _Float16* h2h = (_Float16*)(ws + o); o += (size_t)N*32;   // N*64 halves
  o += (o & 1);                                             // 8B align
  u64* temp0 = (u64*)(ws + o); o += (size_t)E0*2;
  u64* temp1 = (u64*)(ws + o); o += (size_t)E1*2;
  int* iws = (int*)(ws + o);
  size_t io = 0;
  int* rowptr0 = iws + io; io += N + 1;
  int* rowptr1 = iws + io; io += N + 1;
  int* bcnt0   = iws + io; io += NBMAX;  // bcnt0/bcnt1 adjacent: one memset
  int* bcnt1   = iws + io; io += NBMAX;
  int* bbase0  = iws + io; io += NBMAX + 1;
  int* bbase1  = iws + io; io += NBMAX + 1;
  int* bcur0   = iws + io; io += NBMAX;
  int* bcur1   = iws + io; io += NBMAX;
  int* csrc0   = iws + io; io += E0;
  int* csrc1   = iws + io; io += E1;

  dim3 blk(256);
  const int blocksA0 = (E0 + 4095) / 4096;
  const int blocksA1 = (E1 + 4095) / 4096;
  // CSR build: bucket counts -> tiny scan -> bucketed scatter -> bucket-local rowptr
  hipMemsetAsync(bcnt0, 0, 2*NBMAX*sizeof(int), stream);
  k_bhist  <<<1024, blk, 0, stream>>>(dst0, E0, dst1, E1, bcnt0, bcnt1, nb);
  k_bscan  <<<1, 1024, 0, stream>>>(bcnt0, bbase0, bcur0, bcnt1, bbase1, bcur1, nb);
  k_bucketA<<<blocksA0 + blocksA1, blk, 0, stream>>>(
      src0, dst0, bcur0, temp0, E0, blocksA0, src1, dst1, bcur1, temp1, E1, nb);
  k_bucketB2<<<2*nb, blk, 0, stream>>>(temp0, bbase0, rowptr0, csrc0,
                                       temp1, bbase1, rowptr1, csrc1, N, nb);
  // layer 1
  k_gemm1   <<<(N+31)/32, blk, 0, stream>>>(x, W1, a_src1, a_dst1, h1h, es1, ed1, N);
  k_agg1_csr<<<2048, blk, 0, stream>>>(rowptr0, csrc0, es1, ed1, h1h, t2h, N);
  // layer 2
  k_gemm2   <<<(N+31)/32, blk, 0, stream>>>(t2h, W2, a_src2, a_dst2, h2h, es2, ed2, N);
  k_agg2_csr<<<2048, blk, 0, stream>>>(rowptr1, csrc1, es2, ed2, h2h, out, N);
}